// Round 8
// baseline (289.588 us; speedup 1.0000x reference)
//
#include <hip/hip_runtime.h>
#include <stdint.h>

#define B_   4
#define S_   2048
#define D_   512
#define H_   8
#define DH_  64
#define V_   100000
#define P_   256
#define N_   (B_*S_)    // 8192 rows
#define NP_  (B_*P_)    // 1024 rows

typedef _Float16 f16;
typedef _Float16 f16x8 __attribute__((ext_vector_type(8)));
typedef float    f32x4 __attribute__((ext_vector_type(4)));
typedef uint32_t u32x4 __attribute__((ext_vector_type(4)));

#define MFMA16(a,b,c) __builtin_amdgcn_mfma_f32_16x16x32_f16((a),(b),(c),0,0,0)
#define GLDS16(gp, lp) __builtin_amdgcn_global_load_lds( \
    (const __attribute__((address_space(1))) void*)(gp), \
    (__attribute__((address_space(3))) void*)(lp), 16, 0, 0)

// ---------------------------------------------------------------------------
// Weight-conversion job table
// ---------------------------------------------------------------------------
struct WJobs {
  const float* src[10];
  f16* dst[10];
  int K[10], N[10], tiles[10];
};

// ---------------------------------------------------------------------------
// prep kernel: wconv (10240 blocks) + bias concat (10) + embed (4096, 2 rows)
// ---------------------------------------------------------------------------
__global__ __launch_bounds__(256) void prep_kernel(WJobs jobs,
    const float* __restrict__ sbq, const float* __restrict__ sbk,
    const float* __restrict__ sbv, const float* __restrict__ cbk,
    const float* __restrict__ cbv, float* __restrict__ bqkv,
    float* __restrict__ bckv,
    const int* __restrict__ bytes_seq, const float* __restrict__ byte_emb,
    const float* __restrict__ ngram_emb, f16* __restrict__ out16)
{
  int bid = blockIdx.x;
  if (bid < 10240) {
    // ---- weight transpose+cast: fp32 [K][N] -> f16 [N][K] ----
    const int j = bid >> 10, tile = bid & 1023;
    if (tile >= jobs.tiles[j]) return;
    const int K = jobs.K[j], N = jobs.N[j];
    const int ntiles = N >> 5;
    const int kt = (tile / ntiles) << 5, nt = (tile % ntiles) << 5;
    __shared__ float T[32][33];
    const int t = threadIdx.x;
    const float* src = jobs.src[j];
    #pragma unroll
    for (int p = 0; p < 4; p++) {
      int lin = t + p * 256;
      int rr = lin >> 5, cc = lin & 31;
      T[rr][cc] = src[(size_t)(kt + rr) * N + nt + cc];
    }
    __syncthreads();
    f16* dst = jobs.dst[j];
    #pragma unroll
    for (int p = 0; p < 4; p++) {
      int lin = t + p * 256;
      int rr = lin >> 5, cc = lin & 31;
      dst[(size_t)(nt + rr) * K + kt + cc] = (f16)T[cc][rr];
    }
    return;
  }
  bid -= 10240;
  if (bid < 10) {
    // ---- bias concat ----
    int t = bid * 256 + threadIdx.x;
    if (t < 512)       bqkv[t] = sbq[t];
    else if (t < 1024) bqkv[t] = sbk[t - 512];
    else if (t < 1536) bqkv[t] = sbv[t - 1024];
    else if (t < 2048) bckv[t - 1536] = cbk[t - 1536];
    else if (t < 2560) bckv[t - 1536] = cbv[t - 2048];
    return;
  }
  bid -= 10;
  // ---- embedding + n-gram hash (2 rows per block) ----
  const int pos = bid * 2 + (threadIdx.x >> 7);
  const int b = pos / S_, s = pos % S_;
  const int* bs = bytes_seq + (size_t)b * S_;

  int w[8];
  #pragma unroll
  for (int k = 0; k < 8; k++) {
    int p = s - 7 + k;
    w[k] = (p >= 0) ? bs[p] : 0;
  }
  int idx[6];
  #pragma unroll
  for (int j = 0; j < 6; j++) {
    const int n = j + 3;
    int id = 0;
    if (s >= n - 1) {
      uint64_t h = 0;
      for (int k = 0; k < n; k++)
        h += (uint64_t)(uint32_t)w[8 - n + k] << (8 * k);
      long long sh = (long long)h;       // int64 wraparound semantics
      long long r = sh % (long long)V_;  // trunc-mod to floor-mod
      if (r < 0) r += V_;
      id = (int)r;
    }
    idx[j] = id;
  }
  const int d = (threadIdx.x & 127) * 4;
  float4 acc = *(const float4*)(byte_emb + (size_t)bs[s] * D_ + d);
  #pragma unroll
  for (int j = 0; j < 6; j++) {
    const float4 v = *(const float4*)(ngram_emb + ((size_t)j * V_ + idx[j]) * D_ + d);
    acc.x += v.x; acc.y += v.y; acc.z += v.z; acc.w += v.w;
  }
  const float inv7 = 1.0f / 7.0f;
  f16 t4[4];
  t4[0] = (f16)(acc.x * inv7); t4[1] = (f16)(acc.y * inv7);
  t4[2] = (f16)(acc.z * inv7); t4[3] = (f16)(acc.w * inv7);
  *(uint2*)(out16 + (size_t)pos * D_ + d) = *(uint2*)t4;
}

// ---------------------------------------------------------------------------
// f16 MFMA GEMM body: C[M,N] = A[M,K] @ W[K,N] + bias, W TRANSPOSED Bt[N][K].
// 128xBN tile, BK=32, 4 waves, double-buffered global_load_lds.
// rowmap: A row r -> (r>>8)*S_ + rowmap[r] (patch gather fused).
// VTSTART>=0: cols >= VTSTART are written to vt in [b][h][dh][s] layout
// (V^T per head, s contiguous) instead of C.
// ---------------------------------------------------------------------------
template<typename OutT, int RELU, int BN, int VTSTART>
__device__ __forceinline__ void gemm_body(
    const f16* __restrict__ A, const f16* __restrict__ Bt,
    const float* __restrict__ bias, OutT* __restrict__ C,
    int M, int N, int K, const int* __restrict__ rowmap,
    f16* __restrict__ vt, int bmi, int bni)
{
  constexpr int NF = BN / 32;           // N-frags per wave
  __shared__ __align__(16) f16 As[2][128 * 32];
  __shared__ __align__(16) f16 Bs[2][BN * 32];
  const int tid = threadIdx.x;
  const int l = tid & 63;
  const int lo4 = l & 15, hi2 = l >> 4;
  const int w = tid >> 6;
  const int wr = w >> 1, wc = w & 1;
  const int bm = bmi * 128, bn = bni * BN;

  size_t aoff[2];
  #pragma unroll
  for (int i = 0; i < 2; i++) {
    int r = bm + i * 64 + (tid >> 2);
    int ar = rowmap ? ((r >> 8) * S_ + rowmap[r]) : r;
    aoff[i] = (size_t)ar * K + (tid & 3) * 8;
  }

  f32x4 acc[4][NF];
  #pragma unroll
  for (int m = 0; m < 4; m++)
    #pragma unroll
    for (int n = 0; n < NF; n++) acc[m][n] = (f32x4){0.f, 0.f, 0.f, 0.f};

  const int nt = K >> 5;

  #pragma unroll
  for (int i = 0; i < 2; i++)
    GLDS16(A + aoff[i], &As[0][(i * 256 + tid) * 8]);
  #pragma unroll
  for (int i = 0; i < BN / 64; i++) {
    int c = i * 256 + tid;
    GLDS16(Bt + (size_t)(bn + (c >> 2)) * K + (c & 3) * 8, &Bs[0][c * 8]);
  }

  for (int t = 0; t < nt; t++) {
    __syncthreads();
    const int cur = t & 1;
    if (t + 1 < nt) {
      const int k0 = (t + 1) << 5;
      #pragma unroll
      for (int i = 0; i < 2; i++)
        GLDS16(A + aoff[i] + k0, &As[cur ^ 1][(i * 256 + tid) * 8]);
      #pragma unroll
      for (int i = 0; i < BN / 64; i++) {
        int c = i * 256 + tid;
        GLDS16(Bt + (size_t)(bn + (c >> 2)) * K + k0 + (c & 3) * 8, &Bs[cur ^ 1][c * 8]);
      }
    }
    f16x8 af[4], bf[NF];
    const f16* pa = &As[cur][(wr * 64 + lo4) * 32 + hi2 * 8];
    const f16* pb = &Bs[cur][(wc * (BN / 2) + lo4) * 32 + hi2 * 8];
    #pragma unroll
    for (int m = 0; m < 4; m++) af[m] = *(const f16x8*)(pa + m * 16 * 32);
    #pragma unroll
    for (int n = 0; n < NF; n++) bf[n] = *(const f16x8*)(pb + n * 16 * 32);
    #pragma unroll
    for (int m = 0; m < 4; m++)
      #pragma unroll
      for (int n = 0; n < NF; n++)
        acc[m][n] = MFMA16(af[m], bf[n], acc[m][n]);
  }

  if constexpr (VTSTART >= 0) {
    if (bn >= VTSTART) {
      // V^T epilogue: vt[((b*8+h)*64+d)*2048 + s], 4 consecutive s per store
      #pragma unroll
      for (int n = 0; n < NF; n++) {
        const int col = bn + wc * (BN / 2) + n * 16 + lo4;
        const float bcol = bias[col];
        const int dcol = col - VTSTART;
        const size_t vbase = ((size_t)(dcol >> 6) * 64 + (dcol & 63)) << 11;
        #pragma unroll
        for (int m = 0; m < 4; m++) {
          const int row0 = bm + wr * 64 + m * 16 + hi2 * 4;
          f16 t4[4];
          #pragma unroll
          for (int j = 0; j < 4; j++) t4[j] = (f16)(acc[m][n][j] + bcol);
          *(uint2*)(vt + (((size_t)(row0 >> 11) * 8) << 17) + vbase + (row0 & 2047)) = *(uint2*)t4;
        }
      }
      return;
    }
  }

  #pragma unroll
  for (int n = 0; n < NF; n++) {
    const int col = bn + wc * (BN / 2) + n * 16 + lo4;
    const float bcol = bias[col];
    #pragma unroll
    for (int m = 0; m < 4; m++) {
      const int row0 = bm + wr * 64 + m * 16 + hi2 * 4;
      #pragma unroll
      for (int j = 0; j < 4; j++) {
        float v = acc[m][n][j] + bcol;
        if (RELU) v = fmaxf(v, 0.f);
        C[(size_t)(row0 + j) * N + col] = (OutT)v;
      }
    }
  }
}

template<typename OutT, int RELU, int BN, int VTSTART>
__global__ __launch_bounds__(256) void gemm_f16(
    const f16* __restrict__ A, const f16* __restrict__ Bt,
    const float* __restrict__ bias, OutT* __restrict__ C,
    int M, int N, int K, const int* __restrict__ rowmap, f16* __restrict__ vt)
{
  gemm_body<OutT, RELU, BN, VTSTART>(A, Bt, bias, C, M, N, K, rowmap, vt,
                                     blockIdx.x, blockIdx.y);
}

// ---------------------------------------------------------------------------
// merged cKV GEMM (512 blocks, V^T out) + gather-fused cQ GEMM (64 blocks)
// ---------------------------------------------------------------------------
__global__ __launch_bounds__(256) void ckv_cq_kernel(
    const f16* __restrict__ X, const f16* __restrict__ CKVT,
    const float* __restrict__ bckv, f16* __restrict__ CKV,
    f16* __restrict__ vt2, const f16* __restrict__ cWqT,
    const float* __restrict__ cbq, f16* __restrict__ CQ,
    const int* __restrict__ pidx)
{
  int bid = blockIdx.x;
  if (bid < 512) {
    gemm_body<f16, 0, 128, 512>(X, CKVT, bckv, CKV, N_, 1024, 512,
                                nullptr, vt2, bid >> 3, bid & 7);
  } else {
    bid -= 512;
    gemm_body<f16, 0, 64, -1>(X, cWqT, cbq, CQ, NP_, 512, 512,
                              pidx, nullptr, bid >> 3, bid & 7);
  }
}

// ---------------------------------------------------------------------------
// f16 MFMA flash attention, max-free softmax (p = exp2(s), clamp 15), swapped
// QK^T with permuted K-rows; P in registers via cvt_pkrtz + ds_bpermute.
// QG q-groups of 16 rows per wave; K/V fragments read once per tile.
// V comes PRE-TRANSPOSED from global (VT[b][h][d][s]) and is staged by
// global_load_lds into LINEAR LDS with an XOR-swizzled global source
// (read-side swizzle cc^(lo4&7) -> 2-way banks = free).
// Grid 1D: lin = (b*8+h) + 32*qt  (lin%8 = h for XCD L2 locality).
// ---------------------------------------------------------------------------
template<int QG>
__global__ __launch_bounds__(256) void attn_f16(
    const f16* __restrict__ Q, int qs,
    const f16* __restrict__ Kp, int kvs,
    const f16* __restrict__ VT, f16* __restrict__ O, int NQ)
{
  __shared__ __align__(16) f16 Ks[2][64][76];
  __shared__ __align__(16) f16 VtL[2][64 * 64];

  const int tid = threadIdx.x;
  const int w = tid >> 6, l = tid & 63;
  const int lo4 = l & 15, hi2 = l >> 4;
  const int lin = blockIdx.x;
  const int h = lin & 7, b = (lin >> 3) & 3, qt = lin >> 5;

  // Q fragments (B-operand: col=q=lane&15, k = hi2*8+i), pre-scaled (log2 dom)
  const f16 qscale = (f16)0.18033688f;   // 0.125 * log2(e)
  f16x8 qf[QG][2];
  #pragma unroll
  for (int qg = 0; qg < QG; qg++) {
    const int qrow = qt * (64 * QG) + w * (16 * QG) + qg * 16 + lo4;
    const f16* Qp = Q + (size_t)(b * NQ + qrow) * qs + h * DH_ + hi2 * 8;
    qf[qg][0] = *(const f16x8*)(Qp);
    qf[qg][1] = *(const f16x8*)(Qp + 32);
    #pragma unroll
    for (int i = 0; i < 8; i++) { qf[qg][0][i] *= qscale; qf[qg][1][i] *= qscale; }
  }

  // permuted K-row indices for the QK^T A-fragment
  const int g2 = lo4 >> 2, j4 = lo4 & 3;
  const int kvp0 = 8 * g2 + j4;              // nf=0 (own block)
  const int kvp1 = 8 * (g2 ^ 2) + 4 + j4;    // nf=1 (partner block)
  const int pidx = (l ^ 32) << 2;            // bpermute partner index
  const int vswz = lo4 & 7;                  // V read swizzle

  const f16* Kb = Kp + (size_t)b * S_ * kvs + h * DH_;
  const f16* VTbh = VT + (((size_t)(b * 8 + h)) << 17);   // *64*2048

  float lsum[QG];
  f32x4 oacc[QG][4];
  #pragma unroll
  for (int qg = 0; qg < QG; qg++) {
    lsum[qg] = 0.f;
    #pragma unroll
    for (int df = 0; df < 4; df++) oacc[qg][df] = (f32x4){0.f, 0.f, 0.f, 0.f};
  }

  const int r0 = tid >> 3;   // K staging row 0..31
  const int c8 = tid & 7;    // K staging 8-elem col chunk
  const int vr = tid >> 3;   // V slot row  (slot = i*256+tid: r = slot>>3)
  const int vch = tid & 7;   // V slot chunk

  // prologue: stage tile 0
  #pragma unroll
  for (int i = 0; i < 2; i++) {
    int r = i * 32 + vr, ch = vch;
    GLDS16(VTbh + (size_t)r * 2048 + ((ch ^ (r & 7)) * 8), &VtL[0][(i * 256 + tid) * 8]);
  }
  f16x8 kreg[2];
  #pragma unroll
  for (int i = 0; i < 2; i++)
    kreg[i] = *(const f16x8*)(Kb + (size_t)(i * 32 + r0) * kvs + c8 * 8);
  #pragma unroll
  for (int i = 0; i < 2; i++)
    *(f16x8*)(&Ks[0][i * 32 + r0][c8 * 8]) = kreg[i];
  __syncthreads();

  const int NT = S_ / 64;
  int cur = 0;
  for (int t = 0; t < NT; t++) {
    if (t + 1 < NT) {
      const int kt2 = (t + 1) * 64;
      #pragma unroll
      for (int i = 0; i < 2; i++) {
        int r = i * 32 + vr;
        GLDS16(VTbh + (size_t)r * 2048 + kt2 + ((vch ^ (r & 7)) * 8),
               &VtL[cur ^ 1][(i * 256 + tid) * 8]);
      }
      #pragma unroll
      for (int i = 0; i < 2; i++)
        kreg[i] = *(const f16x8*)(Kb + (size_t)(kt2 + i * 32 + r0) * kvs + c8 * 8);
    }
    // S^T = K Q^T (log2 domain); K-fragments shared across q-groups
    f32x4 sacc[QG][4];
    #pragma unroll
    for (int nf = 0; nf < 4; nf++) {
      const int krow = ((nf & 1) ? kvp1 : kvp0) + (nf >> 1) * 32;
      f16x8 kf0 = *(const f16x8*)(&Ks[cur][krow][hi2 * 8]);
      f16x8 kf1 = *(const f16x8*)(&Ks[cur][krow][32 + hi2 * 8]);
      #pragma unroll
      for (int qg = 0; qg < QG; qg++) {
        f32x4 s = (f32x4){0.f, 0.f, 0.f, 0.f};
        s = MFMA16(kf0, qf[qg][0], s);
        s = MFMA16(kf1, qf[qg][1], s);
        sacc[qg][nf] = s;
      }
    }
    // p = exp2(s); per-lane partial row-sum; pack to f16 pairs
    uint32_t packs[QG][4][2];
    #pragma unroll
    for (int qg = 0; qg < QG; qg++)
      #pragma unroll
      for (int nf = 0; nf < 4; nf++) {
        float p0 = exp2f(fminf(sacc[qg][nf][0], 15.f));
        float p1 = exp2f(fminf(sacc[qg][nf][1], 15.f));
        float p2 = exp2f(fminf(sacc[qg][nf][2], 15.f));
        float p3 = exp2f(fminf(sacc[qg][nf][3], 15.f));
        lsum[qg] += (p0 + p1) + (p2 + p3);
        packs[qg][nf][0] = __builtin_bit_cast(uint32_t, __builtin_amdgcn_cvt_pkrtz(p0, p1));
        packs[qg][nf][1] = __builtin_bit_cast(uint32_t, __builtin_amdgcn_cvt_pkrtz(p2, p3));
      }
    // O^T += V^T P^T: V-fragments shared across q-groups
    #pragma unroll
    for (int ks = 0; ks < 2; ks++) {
      f16x8 pb[QG];
      #pragma unroll
      for (int qg = 0; qg < QG; qg++) {
        uint32_t w0 = packs[qg][2 * ks][0];
        uint32_t w1 = packs[qg][2 * ks][1];
        uint32_t w2 = (uint32_t)__builtin_amdgcn_ds_bpermute(pidx, (int)packs[qg][2 * ks + 1][0]);
        uint32_t w3 = (uint32_t)__builtin_amdgcn_ds_bpermute(pidx, (int)packs[qg][2 * ks + 1][1]);
        u32x4 bw = (u32x4){w0, w1, w2, w3};
        pb[qg] = __builtin_bit_cast(f16x8, bw);
      }
      #pragma unroll
      for (int df = 0; df < 4; df++) {
        const int r = df * 16 + lo4;
        const int cc = (ks * 4 + hi2) ^ vswz;
        f16x8 vf = *(const f16x8*)(&VtL[cur][r * 64 + cc * 8]);
        #pragma unroll
        for (int qg = 0; qg < QG; qg++)
          oacc[qg][df] = MFMA16(vf, pb[qg], oacc[qg][df]);
      }
    }
    // write prefetched K into idle buffer; barrier covers GLDS completion too
    if (t + 1 < NT) {
      #pragma unroll
      for (int i = 0; i < 2; i++)
        *(f16x8*)(&Ks[cur ^ 1][i * 32 + r0][c8 * 8]) = kreg[i];
    }
    __syncthreads();
    cur ^= 1;
  }

  #pragma unroll
  for (int qg = 0; qg < QG; qg++) {
    float r = lsum[qg];
    r += __shfl_xor(r, 16, 64);
    r += __shfl_xor(r, 32, 64);
    const float invl = 1.0f / r;
    const int orow = qt * (64 * QG) + w * (16 * QG) + qg * 16 + lo4;
    f16* Ob = O + (size_t)(b * NQ + orow) * D_ + h * DH_ + hi2 * 4;
    #pragma unroll
    for (int df = 0; df < 4; df++) {
      f16 t4[4];
      #pragma unroll
      for (int j = 0; j < 4; j++) t4[j] = (f16)(oacc[qg][df][j] * invl);
      *(uint2*)(Ob + df * 16) = *(uint2*)t4;
    }
  }
}

// ---------------------------------------------------------------------------
// Fused residual + LayerNorm, all-f16 I/O (f32 math inside)
// ---------------------------------------------------------------------------
__global__ __launch_bounds__(128) void ln_kernel(
    const f16* __restrict__ a, const f16* __restrict__ r,
    const float* __restrict__ g, const float* __restrict__ be,
    f16* __restrict__ out)
{
  const int row = blockIdx.x;
  const int t = threadIdx.x;
  const f16* ap = a + (size_t)row * D_ + t * 4;
  const f16* rp = r + (size_t)row * D_ + t * 4;
  uint2 au = *(const uint2*)ap, ru = *(const uint2*)rp;
  f16 a4[4], r4[4];
  *(uint2*)a4 = au; *(uint2*)r4 = ru;
  float x0 = (float)a4[0] + (float)r4[0];
  float x1 = (float)a4[1] + (float)r4[1];
  float x2 = (float)a4[2] + (float)r4[2];
  float x3 = (float)a4[3] + (float)r4[3];
  float sm = x0 + x1 + x2 + x3;
  float sq = x0*x0 + x1*x1 + x2*x2 + x3*x3;
  #pragma unroll
  for (int off = 32; off > 0; off >>= 1) {
    sm += __shfl_down(sm, off, 64);
    sq += __shfl_down(sq, off, 64);
  }
  __shared__ float s0[2], s1[2];
  if ((t & 63) == 0) { s0[t >> 6] = sm; s1[t >> 6] = sq; }
  __syncthreads();
  const float Sm = s0[0] + s0[1];
  const float Sq = s1[0] + s1[1];
  const float mean = Sm * (1.0f / 512.0f);
  const float var  = Sq * (1.0f / 512.0f) - mean * mean;
  const float inv  = rsqrtf(var + 1e-5f);
  const float4 vg = *(const float4*)(g + t * 4);
  const float4 vb = *(const float4*)(be + t * 4);
  f16 o4[4];
  o4[0] = (f16)(vg.x * (x0 - mean) * inv + vb.x);
  o4[1] = (f16)(vg.y * (x1 - mean) * inv + vb.y);
  o4[2] = (f16)(vg.z * (x2 - mean) * inv + vb.z);
  o4[3] = (f16)(vg.w * (x3 - mean) * inv + vb.w);
  *(uint2*)(out + (size_t)row * D_ + t * 4) = *(uint2*)o4;
}

// ---------------------------------------------------------------------------
extern "C" void kernel_launch(void* const* d_in, const int* in_sizes, int n_in,
                              void* d_out, int out_size, void* d_ws, size_t ws_size,
                              hipStream_t stream) {
  const int*   bytes_seq = (const int*)  d_in[0];
  const int*   patch_idx = (const int*)  d_in[1];
  const float* byte_emb  = (const float*)d_in[2];
  const float* ngram_emb = (const float*)d_in[3];
  const float* sWq = (const float*)d_in[4];  const float* sbq = (const float*)d_in[5];
  const float* sWk = (const float*)d_in[6];  const float* sbk = (const float*)d_in[7];
  const float* sWv = (const float*)d_in[8];  const float* sbv = (const float*)d_in[9];
  const float* sWo = (const float*)d_in[10]; const float* sbo = (const float*)d_in[11];
  const float* ln1g = (const float*)d_in[12]; const float* ln1b = (const float*)d_in[13];
  const float* W1 = (const float*)d_in[14];  const float* b1 = (const float*)d_in[15];
  const float* W2 = (const float*)d_in[16];  const float* b2 = (const float*)d_in[17];
  const float* ln2g = (const float*)d_in[18]; const float* ln2b = (const float*)d_in[19];
  const float* cWq = (const float*)d_in[20]; const float* cbq = (const float*)d_in[21];
  const float* cWk = (const float*)d_in[22]; const float* cbk = (const float*)d_in[23];
  const float* cWv = (const float*)d_in[24]; const float* cbv = (const float*)d_in[25];
  const float* cWo = (const float*)d_in[26]; const float* cbo = (const float*)d_in[27];

  char* base = (char*)d_ws;
  const size_t MB = 1u << 20;
  f16* E16     = (f16*)(base + 0 * MB);       // 8 MB
  f16* TMP16   = (f16*)(base + 8 * MB);       // 8 MB (ATproj out, FFN2 out)
  f16* X116    = (f16*)(base + 16 * MB);      // 8 MB
  f16* X216    = (f16*)(base + 24 * MB);      // 8 MB
  f16* QKV16   = (f16*)(base + 32 * MB);      // [8192][1536] = 24 MB (V cols unused)
  f16* AT16    = (f16*)(base + 56 * MB);      // 8 MB
  f16* HID16   = (f16*)(base + 64 * MB);      // [8192][2048] = 32 MB
  f16* CKV16   = (f16*)(base + 96 * MB);      // [8192][1024] = 16 MB (V cols unused)
  f16* CQ16    = (f16*)(base + 112 * MB);     // 1 MB
  f16* CO16    = (f16*)(base + 113 * MB);     // 1 MB
  f16* WT      = (f16*)(base + 114 * MB);     // 8 MB transposed weights
  float* bqkv  = (float*)(base + 123 * MB);   // 1536 f32
  float* bckv  = bqkv + 1536;                 // 1024 f32
  f16* VT      = (f16*)(base + 124 * MB);     // [4][8][64][2048] = 8 MB (self V^T)
  f16* VT2     = (f16*)(base + 132 * MB);     // 8 MB (cross V^T)

  f16* QKVT = WT;                 // [1536][512]: Wq^T | Wk^T | Wv^T
  f16* sWoT = QKVT + 786432;
  f16* W1T  = sWoT + 262144;      // [2048][512]
  f16* W2T  = W1T + 1048576;      // [512][2048]
  f16* cWqT = W2T + 1048576;
  f16* CKVT = cWqT + 262144;      // [1024][512]: cWk^T | cWv^T
  f16* cWoT = CKVT + 524288;

  WJobs wj;
  {
    const float* wsrc[10] = {sWq, sWk, sWv, sWo, W1, W2, cWq, cWk, cWv, cWo};
    f16* wdst[10] = {QKVT, QKVT + 262144, QKVT + 524288, sWoT, W1T, W2T,
                     cWqT, CKVT, CKVT + 262144, cWoT};
    const int wK[10] = {512,512,512,512, 512,2048, 512,512,512,512};
    const int wN[10] = {512,512,512,512, 2048,512, 512,512,512,512};
    for (int i = 0; i < 10; i++) {
      wj.src[i] = wsrc[i]; wj.dst[i] = wdst[i];
      wj.K[i] = wK[i]; wj.N[i] = wN[i];
      wj.tiles[i] = (wK[i] >> 5) * (wN[i] >> 5);
    }
  }

  const dim3 blk256(256), blk128(128);

  // prep: weight conversion + bias concat + embedding, one launch
  prep_kernel<<<10240 + 10 + 4096, blk256, 0, stream>>>(
      wj, sbq, sbk, sbv, cbk, cbv, bqkv, bckv,
      bytes_seq, byte_emb, ngram_emb, E16);

  // fused QKV projection; V part goes straight to VT (per-head V^T)
  gemm_f16<f16, 0, 128, 1024><<<dim3(64, 12), blk256, 0, stream>>>(
      E16, QKVT, bqkv, QKV16, N_, 1536, 512, nullptr, VT);

  // self-attention (Q, K strided views into QKV16; V from VT); 128 q/block
  attn_f16<2><<<512, blk256, 0, stream>>>(QKV16, 1536, QKV16 + 512, 1536, VT, AT16, S_);

  // output projection (f16) + LN1
  gemm_f16<f16, 0, 64, -1><<<dim3(64, 8), blk256, 0, stream>>>(
      AT16, sWoT, sbo, TMP16, N_, 512, 512, nullptr, nullptr);
  ln_kernel<<<N_, blk128, 0, stream>>>(E16, TMP16, ln1g, ln1b, X116);

  // FFN
  gemm_f16<f16, 1, 128, -1><<<dim3(64, 16), blk256, 0, stream>>>(
      X116, W1T, b1, HID16, N_, 2048, 512, nullptr, nullptr);
  gemm_f16<f16, 0, 64, -1><<<dim3(64, 8), blk256, 0, stream>>>(
      HID16, W2T, b2, TMP16, N_, 512, 2048, nullptr, nullptr);
  ln_kernel<<<N_, blk128, 0, stream>>>(X116, TMP16, ln2g, ln2b, X216);

  // cross: fused K|V projection (V^T to VT2) + gather-fused Q proj, one launch
  ckv_cq_kernel<<<576, blk256, 0, stream>>>(
      X216, CKVT, bckv, CKV16, VT2, cWqT, cbq, CQ16, patch_idx);
  attn_f16<1><<<128, blk256, 0, stream>>>(CQ16, 512, CKV16, 1024, VT2, CO16, P_);

  // final projection -> d_out (f32)
  gemm_f16<float, 0, 64, -1><<<dim3(8, 8), blk256, 0, stream>>>(
      CO16, cWoT, cbo, (float*)d_out, NP_, 512, 512, nullptr, nullptr);
}

// Round 9
// 278.889 us; speedup vs baseline: 1.0384x; 1.0384x over previous
//
#include <hip/hip_runtime.h>
#include <stdint.h>

#define B_   4
#define S_   2048
#define D_   512
#define H_   8
#define DH_  64
#define V_   100000
#define P_   256
#define N_   (B_*S_)    // 8192 rows
#define NP_  (B_*P_)    // 1024 rows

typedef _Float16 f16;
typedef _Float16 f16x8 __attribute__((ext_vector_type(8)));
typedef float    f32x4 __attribute__((ext_vector_type(4)));
typedef uint32_t u32x4 __attribute__((ext_vector_type(4)));

#define MFMA16(a,b,c) __builtin_amdgcn_mfma_f32_16x16x32_f16((a),(b),(c),0,0,0)
#define GLDS16(gp, lp) __builtin_amdgcn_global_load_lds( \
    (const __attribute__((address_space(1))) void*)(gp), \
    (__attribute__((address_space(3))) void*)(lp), 16, 0, 0)

// ---------------------------------------------------------------------------
// Weight-conversion job table
// ---------------------------------------------------------------------------
struct WJobs {
  const float* src[10];
  f16* dst[10];
  int K[10], N[10], tiles[10];
};

// ---------------------------------------------------------------------------
// prep kernel: wconv (10240 blocks) + bias concat (10) + embed (4096, 2 rows)
// ---------------------------------------------------------------------------
__global__ __launch_bounds__(256) void prep_kernel(WJobs jobs,
    const float* __restrict__ sbq, const float* __restrict__ sbk,
    const float* __restrict__ sbv, const float* __restrict__ cbk,
    const float* __restrict__ cbv, float* __restrict__ bqkv,
    float* __restrict__ bckv,
    const int* __restrict__ bytes_seq, const float* __restrict__ byte_emb,
    const float* __restrict__ ngram_emb, f16* __restrict__ out16)
{
  int bid = blockIdx.x;
  if (bid < 10240) {
    // ---- weight transpose+cast: fp32 [K][N] -> f16 [N][K] ----
    const int j = bid >> 10, tile = bid & 1023;
    if (tile >= jobs.tiles[j]) return;
    const int K = jobs.K[j], N = jobs.N[j];
    const int ntiles = N >> 5;
    const int kt = (tile / ntiles) << 5, nt = (tile % ntiles) << 5;
    __shared__ float T[32][33];
    const int t = threadIdx.x;
    const float* src = jobs.src[j];
    #pragma unroll
    for (int p = 0; p < 4; p++) {
      int lin = t + p * 256;
      int rr = lin >> 5, cc = lin & 31;
      T[rr][cc] = src[(size_t)(kt + rr) * N + nt + cc];
    }
    __syncthreads();
    f16* dst = jobs.dst[j];
    #pragma unroll
    for (int p = 0; p < 4; p++) {
      int lin = t + p * 256;
      int rr = lin >> 5, cc = lin & 31;
      dst[(size_t)(nt + rr) * K + kt + cc] = (f16)T[cc][rr];
    }
    return;
  }
  bid -= 10240;
  if (bid < 10) {
    // ---- bias concat ----
    int t = bid * 256 + threadIdx.x;
    if (t < 512)       bqkv[t] = sbq[t];
    else if (t < 1024) bqkv[t] = sbk[t - 512];
    else if (t < 1536) bqkv[t] = sbv[t - 1024];
    else if (t < 2048) bckv[t - 1536] = cbk[t - 1536];
    else if (t < 2560) bckv[t - 1536] = cbv[t - 2048];
    return;
  }
  bid -= 10;
  // ---- embedding + n-gram hash (2 rows per block) ----
  const int pos = bid * 2 + (threadIdx.x >> 7);
  const int b = pos / S_, s = pos % S_;
  const int* bs = bytes_seq + (size_t)b * S_;

  int w[8];
  #pragma unroll
  for (int k = 0; k < 8; k++) {
    int p = s - 7 + k;
    w[k] = (p >= 0) ? bs[p] : 0;
  }
  int idx[6];
  #pragma unroll
  for (int j = 0; j < 6; j++) {
    const int n = j + 3;
    int id = 0;
    if (s >= n - 1) {
      uint64_t h = 0;
      for (int k = 0; k < n; k++)
        h += (uint64_t)(uint32_t)w[8 - n + k] << (8 * k);
      long long sh = (long long)h;       // int64 wraparound semantics
      long long r = sh % (long long)V_;  // trunc-mod to floor-mod
      if (r < 0) r += V_;
      id = (int)r;
    }
    idx[j] = id;
  }
  const int d = (threadIdx.x & 127) * 4;
  float4 acc = *(const float4*)(byte_emb + (size_t)bs[s] * D_ + d);
  #pragma unroll
  for (int j = 0; j < 6; j++) {
    const float4 v = *(const float4*)(ngram_emb + ((size_t)j * V_ + idx[j]) * D_ + d);
    acc.x += v.x; acc.y += v.y; acc.z += v.z; acc.w += v.w;
  }
  const float inv7 = 1.0f / 7.0f;
  f16 t4[4];
  t4[0] = (f16)(acc.x * inv7); t4[1] = (f16)(acc.y * inv7);
  t4[2] = (f16)(acc.z * inv7); t4[3] = (f16)(acc.w * inv7);
  *(uint2*)(out16 + (size_t)pos * D_ + d) = *(uint2*)t4;
}

// ---------------------------------------------------------------------------
// f16 MFMA GEMM body: C[M,N] = A[M,K] @ W[K,N] + bias, W TRANSPOSED Bt[N][K].
// 128xBN tile, BK=32, 4 waves, double-buffered global_load_lds.
// K is COMPILE-TIME (full address folding + 8-step unroll).
// rowmap: A row r -> (r>>8)*S_ + rowmap[r] (patch gather fused).
// VTSTART>=0: cols >= VTSTART go to vt in [b][h][dh][s] layout (per-head V^T).
// ---------------------------------------------------------------------------
template<typename OutT, int RELU, int BN, int VTSTART, int K>
__device__ __forceinline__ void gemm_body(
    const f16* __restrict__ A, const f16* __restrict__ Bt,
    const float* __restrict__ bias, OutT* __restrict__ C,
    int N, const int* __restrict__ rowmap,
    f16* __restrict__ vt, int bmi, int bni)
{
  constexpr int NF = BN / 32;           // N-frags per wave
  constexpr int NT = K / 32;            // K-steps
  __shared__ __align__(16) f16 As[2][128 * 32];
  __shared__ __align__(16) f16 Bs[2][BN * 32];
  const int tid = threadIdx.x;
  const int l = tid & 63;
  const int lo4 = l & 15, hi2 = l >> 4;
  const int w = tid >> 6;
  const int wr = w >> 1, wc = w & 1;
  const int bm = bmi * 128, bn = bni * BN;

  const f16* ap[2];
  #pragma unroll
  for (int i = 0; i < 2; i++) {
    int r = bm + i * 64 + (tid >> 2);
    int ar = rowmap ? ((r >> 8) * S_ + rowmap[r]) : r;
    ap[i] = A + (size_t)ar * K + (tid & 3) * 8;
  }
  const f16* bp[BN / 64];
  #pragma unroll
  for (int i = 0; i < BN / 64; i++) {
    int c = i * 256 + tid;
    bp[i] = Bt + (size_t)(bn + (c >> 2)) * K + (c & 3) * 8;
  }

  f32x4 acc[4][NF];
  #pragma unroll
  for (int m = 0; m < 4; m++)
    #pragma unroll
    for (int n = 0; n < NF; n++) acc[m][n] = (f32x4){0.f, 0.f, 0.f, 0.f};

  #pragma unroll
  for (int i = 0; i < 2; i++)
    GLDS16(ap[i], &As[0][(i * 256 + tid) * 8]);
  #pragma unroll
  for (int i = 0; i < BN / 64; i++)
    GLDS16(bp[i], &Bs[0][(i * 256 + tid) * 8]);

  for (int to = 0; to < NT / 8; to++) {
    #pragma unroll
    for (int ti = 0; ti < 8; ti++) {
      const int t = to * 8 + ti;
      __syncthreads();
      const int cur = t & 1;
      if (t + 1 < NT) {
        const int k0 = (t + 1) << 5;
        #pragma unroll
        for (int i = 0; i < 2; i++)
          GLDS16(ap[i] + k0, &As[cur ^ 1][(i * 256 + tid) * 8]);
        #pragma unroll
        for (int i = 0; i < BN / 64; i++)
          GLDS16(bp[i] + k0, &Bs[cur ^ 1][(i * 256 + tid) * 8]);
      }
      f16x8 af[4], bf[NF];
      const f16* pa = &As[cur][(wr * 64 + lo4) * 32 + hi2 * 8];
      const f16* pb = &Bs[cur][(wc * (BN / 2) + lo4) * 32 + hi2 * 8];
      #pragma unroll
      for (int m = 0; m < 4; m++) af[m] = *(const f16x8*)(pa + m * 16 * 32);
      #pragma unroll
      for (int n = 0; n < NF; n++) bf[n] = *(const f16x8*)(pb + n * 16 * 32);
      #pragma unroll
      for (int m = 0; m < 4; m++)
        #pragma unroll
        for (int n = 0; n < NF; n++)
          acc[m][n] = MFMA16(af[m], bf[n], acc[m][n]);
    }
  }

  if constexpr (VTSTART >= 0) {
    if (bn >= VTSTART) {
      // V^T epilogue: vt[((b*8+h)*64+d)*2048 + s]
      #pragma unroll
      for (int n = 0; n < NF; n++) {
        const int col = bn + wc * (BN / 2) + n * 16 + lo4;
        const float bcol = bias[col];
        const int dcol = col - VTSTART;
        const size_t vbase = ((size_t)(dcol >> 6) * 64 + (dcol & 63)) << 11;
        #pragma unroll
        for (int m = 0; m < 4; m++) {
          const int row0 = bm + wr * 64 + m * 16 + hi2 * 4;
          f16 t4[4];
          #pragma unroll
          for (int j = 0; j < 4; j++) t4[j] = (f16)(acc[m][n][j] + bcol);
          *(uint2*)(vt + (((size_t)(row0 >> 11) * 8) << 17) + vbase + (row0 & 2047)) = *(uint2*)t4;
        }
      }
      return;
    }
  }

  #pragma unroll
  for (int n = 0; n < NF; n++) {
    const int col = bn + wc * (BN / 2) + n * 16 + lo4;
    const float bcol = bias[col];
    #pragma unroll
    for (int m = 0; m < 4; m++) {
      const int row0 = bm + wr * 64 + m * 16 + hi2 * 4;
      #pragma unroll
      for (int j = 0; j < 4; j++) {
        float v = acc[m][n][j] + bcol;
        if (RELU) v = fmaxf(v, 0.f);
        C[(size_t)(row0 + j) * N + col] = (OutT)v;
      }
    }
  }
}

template<typename OutT, int RELU, int BN, int VTSTART, int K>
__global__ __launch_bounds__(256) void gemm_f16(
    const f16* __restrict__ A, const f16* __restrict__ Bt,
    const float* __restrict__ bias, OutT* __restrict__ C,
    int N, const int* __restrict__ rowmap, f16* __restrict__ vt)
{
  gemm_body<OutT, RELU, BN, VTSTART, K>(A, Bt, bias, C, N, rowmap, vt,
                                        blockIdx.x, blockIdx.y);
}

// ---------------------------------------------------------------------------
// merged cKV GEMM (512 blocks, V^T out) + gather-fused cQ GEMM (64 blocks)
// ---------------------------------------------------------------------------
__global__ __launch_bounds__(256) void ckv_cq_kernel(
    const f16* __restrict__ X, const f16* __restrict__ CKVT,
    const float* __restrict__ bckv, f16* __restrict__ CKV,
    f16* __restrict__ vt2, const f16* __restrict__ cWqT,
    const float* __restrict__ cbq, f16* __restrict__ CQ,
    const int* __restrict__ pidx)
{
  int bid = blockIdx.x;
  if (bid < 512) {
    gemm_body<f16, 0, 128, 512, 512>(X, CKVT, bckv, CKV, 1024,
                                     nullptr, vt2, bid >> 3, bid & 7);
  } else {
    bid -= 512;
    gemm_body<f16, 0, 64, -1, 512>(X, cWqT, cbq, CQ, 512,
                                   pidx, nullptr, bid >> 3, bid & 7);
  }
}

// ---------------------------------------------------------------------------
// f16 MFMA flash attention, max-free softmax (p = exp2(s), no clamp: scores
// provably |s| << 16 in log2 domain), swapped QK^T with permuted K-rows;
// P in registers via cvt_pkrtz + ds_bpermute. QG q-groups of 16 rows/wave.
// CHUNKS>1: flash-decode split-KV; writes unnormalized f32 O + lsum partials.
// V pre-transposed in global (VT[b][h][d][s]); staged to linear LDS via
// GLDS with XOR-swizzled global source; read with matching swizzle.
// ---------------------------------------------------------------------------
template<int QG, int CHUNKS>
__global__ __launch_bounds__(256) void attn_f16(
    const f16* __restrict__ Q, int qs,
    const f16* __restrict__ Kp, int kvs,
    const f16* __restrict__ VT, f16* __restrict__ O,
    float* __restrict__ Opart, float* __restrict__ Lpart, int NQ)
{
  constexpr int CL = S_ / CHUNKS;      // kv chunk length
  constexpr int NT = CL / 64;
  __shared__ __align__(16) f16 Ks[2][64][76];
  __shared__ __align__(16) f16 VtL[2][64 * 64];

  const int tid = threadIdx.x;
  const int w = tid >> 6, l = tid & 63;
  const int lo4 = l & 15, hi2 = l >> 4;
  const int lin = (CHUNKS == 1) ? blockIdx.x : (blockIdx.x & 127);
  const int c   = (CHUNKS == 1) ? 0 : (int)(blockIdx.x >> 7);
  const int h = lin & 7, b = (lin >> 3) & 3, qt = lin >> 5;

  // Q fragments (B-operand: col=q=lane&15, k = hi2*8+i), pre-scaled (log2 dom)
  const f16 qscale = (f16)0.18033688f;   // 0.125 * log2(e)
  f16x8 qf[QG][2];
  #pragma unroll
  for (int qg = 0; qg < QG; qg++) {
    const int qrow = qt * (64 * QG) + w * (16 * QG) + qg * 16 + lo4;
    const f16* Qp = Q + (size_t)(b * NQ + qrow) * qs + h * DH_ + hi2 * 8;
    qf[qg][0] = *(const f16x8*)(Qp);
    qf[qg][1] = *(const f16x8*)(Qp + 32);
    #pragma unroll
    for (int i = 0; i < 8; i++) { qf[qg][0][i] *= qscale; qf[qg][1][i] *= qscale; }
  }

  const int g2 = lo4 >> 2, j4 = lo4 & 3;
  const int kvp0 = 8 * g2 + j4;              // nf=0 (own block)
  const int kvp1 = 8 * (g2 ^ 2) + 4 + j4;    // nf=1 (partner block)
  const int pidx = (l ^ 32) << 2;            // bpermute partner index
  const int vswz = lo4 & 7;                  // V read swizzle

  const f16* Kb = Kp + ((size_t)b * S_ + c * CL) * kvs + h * DH_;
  const f16* VTbh = VT + (((size_t)(b * 8 + h)) << 17) + c * CL;

  float lsum[QG];
  f32x4 oacc[QG][4];
  #pragma unroll
  for (int qg = 0; qg < QG; qg++) {
    lsum[qg] = 0.f;
    #pragma unroll
    for (int df = 0; df < 4; df++) oacc[qg][df] = (f32x4){0.f, 0.f, 0.f, 0.f};
  }

  const int r0 = tid >> 3;   // K staging row 0..31
  const int c8 = tid & 7;    // staging 8-elem col chunk

  // prologue: stage tile 0
  #pragma unroll
  for (int i = 0; i < 2; i++) {
    int r = i * 32 + r0;
    GLDS16(VTbh + (size_t)r * 2048 + ((c8 ^ (r & 7)) * 8), &VtL[0][(i * 256 + tid) * 8]);
  }
  f16x8 kreg[2];
  #pragma unroll
  for (int i = 0; i < 2; i++)
    kreg[i] = *(const f16x8*)(Kb + (size_t)(i * 32 + r0) * kvs + c8 * 8);
  #pragma unroll
  for (int i = 0; i < 2; i++)
    *(f16x8*)(&Ks[0][i * 32 + r0][c8 * 8]) = kreg[i];
  __syncthreads();

  int cur = 0;
  for (int t = 0; t < NT; t++) {
    if (t + 1 < NT) {
      const int kt2 = (t + 1) * 64;
      #pragma unroll
      for (int i = 0; i < 2; i++) {
        int r = i * 32 + r0;
        GLDS16(VTbh + (size_t)r * 2048 + kt2 + ((c8 ^ (r & 7)) * 8),
               &VtL[cur ^ 1][(i * 256 + tid) * 8]);
      }
      #pragma unroll
      for (int i = 0; i < 2; i++)
        kreg[i] = *(const f16x8*)(Kb + (size_t)(kt2 + i * 32 + r0) * kvs + c8 * 8);
    }
    // S^T = K Q^T (log2 domain); K-fragments shared across q-groups
    f32x4 sacc[QG][4];
    #pragma unroll
    for (int nf = 0; nf < 4; nf++) {
      const int krow = ((nf & 1) ? kvp1 : kvp0) + (nf >> 1) * 32;
      f16x8 kf0 = *(const f16x8*)(&Ks[cur][krow][hi2 * 8]);
      f16x8 kf1 = *(const f16x8*)(&Ks[cur][krow][32 + hi2 * 8]);
      #pragma unroll
      for (int qg = 0; qg < QG; qg++) {
        f32x4 s = (f32x4){0.f, 0.f, 0.f, 0.f};
        s = MFMA16(kf0, qf[qg][0], s);
        s = MFMA16(kf1, qf[qg][1], s);
        sacc[qg][nf] = s;
      }
    }
    // p = exp2(s); per-lane partial row-sum; pack to f16 pairs
    uint32_t packs[QG][4][2];
    #pragma unroll
    for (int qg = 0; qg < QG; qg++)
      #pragma unroll
      for (int nf = 0; nf < 4; nf++) {
        float p0 = exp2f(sacc[qg][nf][0]);
        float p1 = exp2f(sacc[qg][nf][1]);
        float p2 = exp2f(sacc[qg][nf][2]);
        float p3 = exp2f(sacc[qg][nf][3]);
        lsum[qg] += (p0 + p1) + (p2 + p3);
        packs[qg][nf][0] = __builtin_bit_cast(uint32_t, __builtin_amdgcn_cvt_pkrtz(p0, p1));
        packs[qg][nf][1] = __builtin_bit_cast(uint32_t, __builtin_amdgcn_cvt_pkrtz(p2, p3));
      }
    // O^T += V^T P^T: V-fragments shared across q-groups
    #pragma unroll
    for (int ks = 0; ks < 2; ks++) {
      f16x8 pb[QG];
      #pragma unroll
      for (int qg = 0; qg < QG; qg++) {
        uint32_t w0 = packs[qg][2 * ks][0];
        uint32_t w1 = packs[qg][2 * ks][1];
        uint32_t w2 = (uint32_t)__builtin_amdgcn_ds_bpermute(pidx, (int)packs[qg][2 * ks + 1][0]);
        uint32_t w3 = (uint32_t)__builtin_amdgcn_ds_bpermute(pidx, (int)packs[qg][2 * ks + 1][1]);
        u32x4 bw = (u32x4){w0, w1, w2, w3};
        pb[qg] = __builtin_bit_cast(f16x8, bw);
      }
      #pragma unroll
      for (int df = 0; df < 4; df++) {
        const int r = df * 16 + lo4;
        const int cc = (ks * 4 + hi2) ^ vswz;
        f16x8 vf = *(const f16x8*)(&VtL[cur][r * 64 + cc * 8]);
        #pragma unroll
        for (int qg = 0; qg < QG; qg++)
          oacc[qg][df] = MFMA16(vf, pb[qg], oacc[qg][df]);
      }
    }
    if (t + 1 < NT) {
      #pragma unroll
      for (int i = 0; i < 2; i++)
        *(f16x8*)(&Ks[cur ^ 1][i * 32 + r0][c8 * 8]) = kreg[i];
    }
    __syncthreads();
    cur ^= 1;
  }

  #pragma unroll
  for (int qg = 0; qg < QG; qg++) {
    float r = lsum[qg];
    r += __shfl_xor(r, 16, 64);
    r += __shfl_xor(r, 32, 64);
    const int orow = qt * (64 * QG) + w * (16 * QG) + qg * 16 + lo4;
    if constexpr (CHUNKS == 1) {
      const float invl = 1.0f / r;
      f16* Ob = O + (size_t)(b * NQ + orow) * D_ + h * DH_ + hi2 * 4;
      #pragma unroll
      for (int df = 0; df < 4; df++) {
        f16 t4[4];
        #pragma unroll
        for (int j = 0; j < 4; j++) t4[j] = (f16)(oacc[qg][df][j] * invl);
        *(uint2*)(Ob + df * 16) = *(uint2*)t4;
      }
    } else {
      // unnormalized f32 partials + lsum (max-free softmax is associative)
      float* Op = Opart + ((size_t)c * NP_ + b * NQ + orow) * D_ + h * DH_ + hi2 * 4;
      #pragma unroll
      for (int df = 0; df < 4; df++) {
        float4 v = {oacc[qg][df][0], oacc[qg][df][1], oacc[qg][df][2], oacc[qg][df][3]};
        *(float4*)(Op + df * 16) = v;
      }
      if (hi2 == 0)
        Lpart[((size_t)c * NP_ + b * NQ + orow) * H_ + h] = r;
    }
  }
}

// ---------------------------------------------------------------------------
// combine split-KV partials: CO[row][col] = sum_c O_c / sum_c l_c
// ---------------------------------------------------------------------------
__global__ __launch_bounds__(128) void attn_reduce(
    const float* __restrict__ Opart, const float* __restrict__ Lpart,
    f16* __restrict__ CO)
{
  const int row = blockIdx.x;            // 0..NP_-1
  const int col = threadIdx.x * 4;
  const int h = col >> 6;
  float4 o = {0.f, 0.f, 0.f, 0.f};
  float ls = 0.f;
  #pragma unroll
  for (int c = 0; c < 4; c++) {
    const float4 v = *(const float4*)(Opart + ((size_t)c * NP_ + row) * D_ + col);
    o.x += v.x; o.y += v.y; o.z += v.z; o.w += v.w;
    ls += Lpart[((size_t)c * NP_ + row) * H_ + h];
  }
  const float inv = 1.0f / ls;
  f16 t4[4];
  t4[0] = (f16)(o.x * inv); t4[1] = (f16)(o.y * inv);
  t4[2] = (f16)(o.z * inv); t4[3] = (f16)(o.w * inv);
  *(uint2*)(CO + (size_t)row * D_ + col) = *(uint2*)t4;
}

// ---------------------------------------------------------------------------
// Fused residual + LayerNorm, all-f16 I/O (f32 math inside), 2 rows/block
// ---------------------------------------------------------------------------
__global__ __launch_bounds__(256) void ln_kernel(
    const f16* __restrict__ a, const f16* __restrict__ r,
    const float* __restrict__ g, const float* __restrict__ be,
    f16* __restrict__ out)
{
  const int row = blockIdx.x * 2 + (threadIdx.x >> 7);
  const int t = threadIdx.x & 127;
  const f16* ap = a + (size_t)row * D_ + t * 4;
  const f16* rp = r + (size_t)row * D_ + t * 4;
  uint2 au = *(const uint2*)ap, ru = *(const uint2*)rp;
  f16 a4[4], r4[4];
  *(uint2*)a4 = au; *(uint2*)r4 = ru;
  float x0 = (float)a4[0] + (float)r4[0];
  float x1 = (float)a4[1] + (float)r4[1];
  float x2 = (float)a4[2] + (float)r4[2];
  float x3 = (float)a4[3] + (float)r4[3];
  float sm = x0 + x1 + x2 + x3;
  float sq = x0*x0 + x1*x1 + x2*x2 + x3*x3;
  #pragma unroll
  for (int off = 32; off > 0; off >>= 1) {
    sm += __shfl_down(sm, off, 64);
    sq += __shfl_down(sq, off, 64);
  }
  __shared__ float s0[4], s1[4];
  if ((threadIdx.x & 63) == 0) { s0[threadIdx.x >> 6] = sm; s1[threadIdx.x >> 6] = sq; }
  __syncthreads();
  const int base = (threadIdx.x >> 7) * 2;
  const float Sm = s0[base] + s0[base + 1];
  const float Sq = s1[base] + s1[base + 1];
  const float mean = Sm * (1.0f / 512.0f);
  const float var  = Sq * (1.0f / 512.0f) - mean * mean;
  const float inv  = rsqrtf(var + 1e-5f);
  const float4 vg = *(const float4*)(g + t * 4);
  const float4 vb = *(const float4*)(be + t * 4);
  f16 o4[4];
  o4[0] = (f16)(vg.x * (x0 - mean) * inv + vb.x);
  o4[1] = (f16)(vg.y * (x1 - mean) * inv + vb.y);
  o4[2] = (f16)(vg.z * (x2 - mean) * inv + vb.z);
  o4[3] = (f16)(vg.w * (x3 - mean) * inv + vb.w);
  *(uint2*)(out + (size_t)row * D_ + t * 4) = *(uint2*)o4;
}

// ---------------------------------------------------------------------------
extern "C" void kernel_launch(void* const* d_in, const int* in_sizes, int n_in,
                              void* d_out, int out_size, void* d_ws, size_t ws_size,
                              hipStream_t stream) {
  const int*   bytes_seq = (const int*)  d_in[0];
  const int*   patch_idx = (const int*)  d_in[1];
  const float* byte_emb  = (const float*)d_in[2];
  const float* ngram_emb = (const float*)d_in[3];
  const float* sWq = (const float*)d_in[4];  const float* sbq = (const float*)d_in[5];
  const float* sWk = (const float*)d_in[6];  const float* sbk = (const float*)d_in[7];
  const float* sWv = (const float*)d_in[8];  const float* sbv = (const float*)d_in[9];
  const float* sWo = (const float*)d_in[10]; const float* sbo = (const float*)d_in[11];
  const float* ln1g = (const float*)d_in[12]; const float* ln1b = (const float*)d_in[13];
  const float* W1 = (const float*)d_in[14];  const float* b1 = (const float*)d_in[15];
  const float* W2 = (const float*)d_in[16];  const float* b2 = (const float*)d_in[17];
  const float* ln2g = (const float*)d_in[18]; const float* ln2b = (const float*)d_in[19];
  const float* cWq = (const float*)d_in[20]; const float* cbq = (const float*)d_in[21];
  const float* cWk = (const float*)d_in[22]; const float* cbk = (const float*)d_in[23];
  const float* cWv = (const float*)d_in[24]; const float* cbv = (const float*)d_in[25];
  const float* cWo = (const float*)d_in[26]; const float* cbo = (const float*)d_in[27];

  char* base = (char*)d_ws;
  const size_t MB = 1u << 20;
  f16* E16     = (f16*)(base + 0 * MB);       // 8 MB
  f16* TMP16   = (f16*)(base + 8 * MB);       // 8 MB
  f16* X116    = (f16*)(base + 16 * MB);      // 8 MB
  f16* X216    = (f16*)(base + 24 * MB);      // 8 MB
  f16* QKV16   = (f16*)(base + 32 * MB);      // [8192][1536] = 24 MB (V cols unused)
  f16* AT16    = (f16*)(base + 56 * MB);      // 8 MB
  f16* HID16   = (f16*)(base + 64 * MB);      // [8192][2048] = 32 MB
  f16* CKV16   = (f16*)(base + 96 * MB);      // [8192][1024] = 16 MB (V cols unused)
  f16* CQ16    = (f16*)(base + 112 * MB);     // 1 MB
  f16* CO16    = (f16*)(base + 113 * MB);     // 1 MB
  f16* WT      = (f16*)(base + 114 * MB);     // 8 MB transposed weights
  float* bqkv  = (float*)(base + 123 * MB);   // 1536 f32
  float* bckv  = bqkv + 1536;                 // 1024 f32
  f16* VT      = (f16*)(base + 124 * MB);     // [4][8][64][2048] = 8 MB (self V^T)
  f16* VT2     = (f16*)(base + 132 * MB);     // 8 MB (cross V^T)
  float* OPART = (float*)(base + 140 * MB);   // [4][1024][512] f32 = 8 MB
  float* LPART = (float*)(base + 148 * MB);   // [4][1024][8] f32 = 128 KB

  f16* QKVT = WT;                 // [1536][512]: Wq^T | Wk^T | Wv^T
  f16* sWoT = QKVT + 786432;
  f16* W1T  = sWoT + 262144;      // [2048][512]
  f16* W2T  = W1T + 1048576;      // [512][2048]
  f16* cWqT = W2T + 1048576;
  f16* CKVT = cWqT + 262144;      // [1024][512]: cWk^T | cWv^T
  f16* cWoT = CKVT + 524288;

  WJobs wj;
  {
    const float* wsrc[10] = {sWq, sWk, sWv, sWo, W1, W2, cWq, cWk, cWv, cWo};
    f16* wdst[10] = {QKVT, QKVT + 262144, QKVT + 524288, sWoT, W1T, W2T,
                     cWqT, CKVT, CKVT + 262144, cWoT};
    const int wK[10] = {512,512,512,512, 512,2048, 512,512,512,512};
    const int wN[10] = {512,512,512,512, 2048,512, 512,512,512,512};
    for (int i = 0; i < 10; i++) {
      wj.src[i] = wsrc[i]; wj.dst[i] = wdst[i];
      wj.K[i] = wK[i]; wj.N[i] = wN[i];
      wj.tiles[i] = (wK[i] >> 5) * (wN[i] >> 5);
    }
  }

  const dim3 blk256(256), blk128(128);

  prep_kernel<<<10240 + 10 + 4096, blk256, 0, stream>>>(
      wj, sbq, sbk, sbv, cbk, cbv, bqkv, bckv,
      bytes_seq, byte_emb, ngram_emb, E16);

  // fused QKV projection; V part straight to VT (per-head V^T)
  gemm_f16<f16, 0, 128, 1024, 512><<<dim3(64, 12), blk256, 0, stream>>>(
      E16, QKVT, bqkv, QKV16, 1536, nullptr, VT);

  // self-attention (128 q/block)
  attn_f16<2, 1><<<512, blk256, 0, stream>>>(
      QKV16, 1536, QKV16 + 512, 1536, VT, AT16, nullptr, nullptr, S_);

  // output projection + LN1
  gemm_f16<f16, 0, 64, -1, 512><<<dim3(64, 8), blk256, 0, stream>>>(
      AT16, sWoT, sbo, TMP16, 512, nullptr, nullptr);
  ln_kernel<<<N_/2, blk256, 0, stream>>>(E16, TMP16, ln1g, ln1b, X116);

  // FFN
  gemm_f16<f16, 1, 128, -1, 512><<<dim3(64, 16), blk256, 0, stream>>>(
      X116, W1T, b1, HID16, 2048, nullptr, nullptr);
  gemm_f16<f16, 0, 64, -1, 2048><<<dim3(64, 8), blk256, 0, stream>>>(
      HID16, W2T, b2, TMP16, 512, nullptr, nullptr);
  ln_kernel<<<N_/2, blk256, 0, stream>>>(X116, TMP16, ln2g, ln2b, X216);

  // cross: fused K|V projection (V^T to VT2) + gather-fused Q proj
  ckv_cq_kernel<<<576, blk256, 0, stream>>>(
      X216, CKVT, bckv, CKV16, VT2, cWqT, cbq, CQ16, patch_idx);
  // cross attention, split-KV x4 (flash-decode), then combine
  attn_f16<1, 4><<<512, blk256, 0, stream>>>(
      CQ16, 512, CKV16, 1024, VT2, nullptr, OPART, LPART, P_);
  attn_reduce<<<NP_, blk128, 0, stream>>>(OPART, LPART, CO16);

  // final projection -> d_out (f32)
  gemm_f16<float, 0, 64, -1, 512><<<dim3(8, 8), blk256, 0, stream>>>(
      CO16, cWoT, cbo, (float*)d_out, 512, nullptr, nullptr);
}

// Round 10
// 277.305 us; speedup vs baseline: 1.0443x; 1.0057x over previous
//
#include <hip/hip_runtime.h>
#include <stdint.h>

#define B_   4
#define S_   2048
#define D_   512
#define H_   8
#define DH_  64
#define V_   100000
#define P_   256
#define N_   (B_*S_)    // 8192 rows
#define NP_  (B_*P_)    // 1024 rows

typedef _Float16 f16;
typedef _Float16 f16x8 __attribute__((ext_vector_type(8)));
typedef float    f32x4 __attribute__((ext_vector_type(4)));
typedef uint32_t u32x4 __attribute__((ext_vector_type(4)));

#define MFMA16(a,b,c) __builtin_amdgcn_mfma_f32_16x16x32_f16((a),(b),(c),0,0,0)
#define GLDS16(gp, lp) __builtin_amdgcn_global_load_lds( \
    (const __attribute__((address_space(1))) void*)(gp), \
    (__attribute__((address_space(3))) void*)(lp), 16, 0, 0)

// ---------------------------------------------------------------------------
// Weight-conversion job table
// ---------------------------------------------------------------------------
struct WJobs {
  const float* src[10];
  f16* dst[10];
  int K[10], N[10], tiles[10];
};

// ---------------------------------------------------------------------------
// prep kernel: wconv (10240 blocks) + bias concat (10) + embed (4096, 2 rows)
// ---------------------------------------------------------------------------
__global__ __launch_bounds__(256) void prep_kernel(WJobs jobs,
    const float* __restrict__ sbq, const float* __restrict__ sbk,
    const float* __restrict__ sbv, const float* __restrict__ cbk,
    const float* __restrict__ cbv, float* __restrict__ bqkv,
    float* __restrict__ bckv,
    const int* __restrict__ bytes_seq, const float* __restrict__ byte_emb,
    const float* __restrict__ ngram_emb, f16* __restrict__ out16)
{
  int bid = blockIdx.x;
  if (bid < 10240) {
    // ---- weight transpose+cast: fp32 [K][N] -> f16 [N][K] ----
    const int j = bid >> 10, tile = bid & 1023;
    if (tile >= jobs.tiles[j]) return;
    const int K = jobs.K[j], N = jobs.N[j];
    const int ntiles = N >> 5;
    const int kt = (tile / ntiles) << 5, nt = (tile % ntiles) << 5;
    __shared__ float T[32][33];
    const int t = threadIdx.x;
    const float* src = jobs.src[j];
    #pragma unroll
    for (int p = 0; p < 4; p++) {
      int lin = t + p * 256;
      int rr = lin >> 5, cc = lin & 31;
      T[rr][cc] = src[(size_t)(kt + rr) * N + nt + cc];
    }
    __syncthreads();
    f16* dst = jobs.dst[j];
    #pragma unroll
    for (int p = 0; p < 4; p++) {
      int lin = t + p * 256;
      int rr = lin >> 5, cc = lin & 31;
      dst[(size_t)(nt + rr) * K + kt + cc] = (f16)T[cc][rr];
    }
    return;
  }
  bid -= 10240;
  if (bid < 10) {
    // ---- bias concat ----
    int t = bid * 256 + threadIdx.x;
    if (t < 512)       bqkv[t] = sbq[t];
    else if (t < 1024) bqkv[t] = sbk[t - 512];
    else if (t < 1536) bqkv[t] = sbv[t - 1024];
    else if (t < 2048) bckv[t - 1536] = cbk[t - 1536];
    else if (t < 2560) bckv[t - 1536] = cbv[t - 2048];
    return;
  }
  bid -= 10;
  // ---- embedding + n-gram hash (2 rows per block) ----
  const int pos = bid * 2 + (threadIdx.x >> 7);
  const int b = pos / S_, s = pos % S_;
  const int* bs = bytes_seq + (size_t)b * S_;

  int w[8];
  #pragma unroll
  for (int k = 0; k < 8; k++) {
    int p = s - 7 + k;
    w[k] = (p >= 0) ? bs[p] : 0;
  }
  int idx[6];
  #pragma unroll
  for (int j = 0; j < 6; j++) {
    const int n = j + 3;
    int id = 0;
    if (s >= n - 1) {
      uint64_t h = 0;
      for (int k = 0; k < n; k++)
        h += (uint64_t)(uint32_t)w[8 - n + k] << (8 * k);
      long long sh = (long long)h;       // int64 wraparound semantics
      long long r = sh % (long long)V_;  // trunc-mod to floor-mod
      if (r < 0) r += V_;
      id = (int)r;
    }
    idx[j] = id;
  }
  const int d = (threadIdx.x & 127) * 4;
  float4 acc = *(const float4*)(byte_emb + (size_t)bs[s] * D_ + d);
  #pragma unroll
  for (int j = 0; j < 6; j++) {
    const float4 v = *(const float4*)(ngram_emb + ((size_t)j * V_ + idx[j]) * D_ + d);
    acc.x += v.x; acc.y += v.y; acc.z += v.z; acc.w += v.w;
  }
  const float inv7 = 1.0f / 7.0f;
  f16 t4[4];
  t4[0] = (f16)(acc.x * inv7); t4[1] = (f16)(acc.y * inv7);
  t4[2] = (f16)(acc.z * inv7); t4[3] = (f16)(acc.w * inv7);
  *(uint2*)(out16 + (size_t)pos * D_ + d) = *(uint2*)t4;
}

// ---------------------------------------------------------------------------
// f16 MFMA GEMM body (C^T accumulation): acc = mfma(bf, af) so each thread
// holds 4 CONSECUTIVE COLUMNS of one row -> packed uint2/float4 stores.
// 128xBN tile, BK=32, 4 waves, double-buffered global_load_lds, K compile-time.
// lda/ldb: row strides of A / Bt (differ from K for split-K chunks).
// rowmap: A row r -> (r>>8)*S_ + rowmap[r] (patch gather fused).
// VTSTART>=0: cols >= VTSTART go to vt in [b][h][dh][s] layout (per-head V^T).
// bias may be nullptr (split-K partials; bias added in reduce).
// ---------------------------------------------------------------------------
template<typename OutT, int RELU, int BN, int VTSTART, int K>
__device__ __forceinline__ void gemm_body(
    const f16* __restrict__ A, const f16* __restrict__ Bt,
    const float* __restrict__ bias, OutT* __restrict__ C,
    int N, const int* __restrict__ rowmap,
    f16* __restrict__ vt, int bmi, int bni, int lda, int ldb)
{
  constexpr int NF = BN / 32;           // N-frags per wave
  constexpr int NT = K / 32;            // K-steps
  constexpr int U  = (NT < 8) ? NT : 8; // unroll factor
  __shared__ __align__(16) f16 As[2][128 * 32];
  __shared__ __align__(16) f16 Bs[2][BN * 32];
  const int tid = threadIdx.x;
  const int l = tid & 63;
  const int lo4 = l & 15, hi2 = l >> 4;
  const int w = tid >> 6;
  const int wr = w >> 1, wc = w & 1;
  const int bm = bmi * 128, bn = bni * BN;

  const f16* ap[2];
  #pragma unroll
  for (int i = 0; i < 2; i++) {
    int r = bm + i * 64 + (tid >> 2);
    int ar = rowmap ? ((r >> 8) * S_ + rowmap[r]) : r;
    ap[i] = A + (size_t)ar * lda + (tid & 3) * 8;
  }
  const f16* bp[BN / 64];
  #pragma unroll
  for (int i = 0; i < BN / 64; i++) {
    int c = i * 256 + tid;
    bp[i] = Bt + (size_t)(bn + (c >> 2)) * ldb + (tid & 3) * 8;
  }

  f32x4 acc[4][NF];
  #pragma unroll
  for (int m = 0; m < 4; m++)
    #pragma unroll
    for (int n = 0; n < NF; n++) acc[m][n] = (f32x4){0.f, 0.f, 0.f, 0.f};

  #pragma unroll
  for (int i = 0; i < 2; i++)
    GLDS16(ap[i], &As[0][(i * 256 + tid) * 8]);
  #pragma unroll
  for (int i = 0; i < BN / 64; i++)
    GLDS16(bp[i], &Bs[0][(i * 256 + tid) * 8]);

  for (int to = 0; to < NT / U; to++) {
    #pragma unroll
    for (int ti = 0; ti < U; ti++) {
      const int t = to * U + ti;
      __syncthreads();
      const int cur = t & 1;
      if (t + 1 < NT) {
        const int k0 = (t + 1) << 5;
        #pragma unroll
        for (int i = 0; i < 2; i++)
          GLDS16(ap[i] + k0, &As[cur ^ 1][(i * 256 + tid) * 8]);
        #pragma unroll
        for (int i = 0; i < BN / 64; i++)
          GLDS16(bp[i] + k0, &Bs[cur ^ 1][(i * 256 + tid) * 8]);
      }
      f16x8 af[4], bf[NF];
      const f16* pa = &As[cur][(wr * 64 + lo4) * 32 + hi2 * 8];
      const f16* pb = &Bs[cur][(wc * (BN / 2) + lo4) * 32 + hi2 * 8];
      #pragma unroll
      for (int m = 0; m < 4; m++) af[m] = *(const f16x8*)(pa + m * 16 * 32);
      #pragma unroll
      for (int n = 0; n < NF; n++) bf[n] = *(const f16x8*)(pb + n * 16 * 32);
      #pragma unroll
      for (int m = 0; m < 4; m++)
        #pragma unroll
        for (int n = 0; n < NF; n++)
          acc[m][n] = MFMA16(bf[n], af[m], acc[m][n]);   // C^T: swap operands
    }
  }

  // SWAPPED C/D layout: product row = C-col = n*16 + hi2*4 + j,
  //                     product col = C-row = m*16 + lo4.
  if constexpr (VTSTART >= 0) {
    if (bn >= VTSTART) {
      // V^T epilogue: vt[((b*8+h)*64+d)*2048 + s]; scalar stores (d varies j)
      #pragma unroll
      for (int n = 0; n < NF; n++) {
        const int col0 = bn + wc * (BN / 2) + n * 16 + hi2 * 4;
        float bb[4] = {0.f, 0.f, 0.f, 0.f};
        if (bias) *(float4*)bb = *(const float4*)(bias + col0);
        #pragma unroll
        for (int m = 0; m < 4; m++) {
          const int s = bm + wr * 64 + m * 16 + lo4;
          #pragma unroll
          for (int j = 0; j < 4; j++) {
            const int dcol = col0 + j - VTSTART;
            vt[(((size_t)(s >> 11) * 8 + (dcol >> 6)) << 17) +
               ((size_t)(dcol & 63) << 11) + (s & 2047)] =
                (f16)(acc[m][n][j] + bb[j]);
          }
        }
      }
      return;
    }
  }

  #pragma unroll
  for (int n = 0; n < NF; n++) {
    const int col0 = bn + wc * (BN / 2) + n * 16 + hi2 * 4;
    float bb[4] = {0.f, 0.f, 0.f, 0.f};
    if (bias) *(float4*)bb = *(const float4*)(bias + col0);
    #pragma unroll
    for (int m = 0; m < 4; m++) {
      const int row = bm + wr * 64 + m * 16 + lo4;
      float v[4];
      #pragma unroll
      for (int j = 0; j < 4; j++) {
        v[j] = acc[m][n][j] + bb[j];
        if (RELU) v[j] = fmaxf(v[j], 0.f);
      }
      if constexpr (sizeof(OutT) == 2) {
        f16 t4[4];
        #pragma unroll
        for (int j = 0; j < 4; j++) t4[j] = (f16)v[j];
        *(uint2*)((f16*)C + (size_t)row * N + col0) = *(uint2*)t4;
      } else {
        float4 t4 = {v[0], v[1], v[2], v[3]};
        *(float4*)((float*)C + (size_t)row * N + col0) = t4;
      }
    }
  }
}

template<typename OutT, int RELU, int BN, int VTSTART, int K>
__global__ __launch_bounds__(256) void gemm_f16(
    const f16* __restrict__ A, const f16* __restrict__ Bt,
    const float* __restrict__ bias, OutT* __restrict__ C,
    int N, const int* __restrict__ rowmap, f16* __restrict__ vt)
{
  gemm_body<OutT, RELU, BN, VTSTART, K>(A, Bt, bias, C, N, rowmap, vt,
                                        blockIdx.x, blockIdx.y, K, K);
}

// ---------------------------------------------------------------------------
// merged cKV GEMM (512 blocks, V^T out) + gather-fused cQ GEMM (64 blocks)
// ---------------------------------------------------------------------------
__global__ __launch_bounds__(256) void ckv_cq_kernel(
    const f16* __restrict__ X, const f16* __restrict__ CKVT,
    const float* __restrict__ bckv, f16* __restrict__ CKV,
    f16* __restrict__ vt2, const f16* __restrict__ cWqT,
    const float* __restrict__ cbq, f16* __restrict__ CQ,
    const int* __restrict__ pidx)
{
  int bid = blockIdx.x;
  if (bid < 512) {
    gemm_body<f16, 0, 128, 512, 512>(X, CKVT, bckv, CKV, 1024,
                                     nullptr, vt2, bid >> 3, bid & 7, 512, 512);
  } else {
    bid -= 512;
    gemm_body<f16, 0, 64, -1, 512>(X, cWqT, cbq, CQ, 512,
                                   pidx, nullptr, bid >> 3, bid & 7, 512, 512);
  }
}

// ---------------------------------------------------------------------------
// final projection, split-K x4: partial[z] = CO[:, z*128:(z+1)*128] @ W-chunk
// ---------------------------------------------------------------------------
__global__ __launch_bounds__(256) void co_splitk(
    const f16* __restrict__ A, const f16* __restrict__ Bt,
    float* __restrict__ part)
{
  const int z = blockIdx.z;
  gemm_body<float, 0, 64, -1, 128>(A + z * 128, Bt + z * 128, nullptr,
      part + (size_t)z * NP_ * 512, 512, nullptr, nullptr,
      blockIdx.x, blockIdx.y, 512, 512);
}

__global__ __launch_bounds__(128) void co_reduce(
    const float* __restrict__ part, const float* __restrict__ bias,
    float* __restrict__ out)
{
  const int row = blockIdx.x;
  const int col = threadIdx.x * 4;
  float4 s = *(const float4*)(bias + col);
  #pragma unroll
  for (int c = 0; c < 4; c++) {
    const float4 v = *(const float4*)(part + ((size_t)c * NP_ + row) * 512 + col);
    s.x += v.x; s.y += v.y; s.z += v.z; s.w += v.w;
  }
  *(float4*)(out + (size_t)row * 512 + col) = s;
}

// ---------------------------------------------------------------------------
// f16 MFMA flash attention, max-free softmax (p = exp2(s)), swapped QK^T with
// permuted K-rows; P in registers via cvt_pkrtz + ds_bpermute. QG q-groups.
// CHUNKS>1: flash-decode split-KV, unnormalized f32 partials + lsum.
// V pre-transposed in global (VT[b][h][d][s]); staged to linear LDS via
// GLDS with XOR-swizzled global source; read with matching swizzle.
// ---------------------------------------------------------------------------
template<int QG, int CHUNKS>
__global__ __launch_bounds__(256) void attn_f16(
    const f16* __restrict__ Q, int qs,
    const f16* __restrict__ Kp, int kvs,
    const f16* __restrict__ VT, f16* __restrict__ O,
    float* __restrict__ Opart, float* __restrict__ Lpart, int NQ)
{
  constexpr int CL = S_ / CHUNKS;      // kv chunk length
  constexpr int NT = CL / 64;
  __shared__ __align__(16) f16 Ks[2][64][76];
  __shared__ __align__(16) f16 VtL[2][64 * 64];

  const int tid = threadIdx.x;
  const int w = tid >> 6, l = tid & 63;
  const int lo4 = l & 15, hi2 = l >> 4;
  const int lin = (CHUNKS == 1) ? blockIdx.x : (blockIdx.x & 127);
  const int c   = (CHUNKS == 1) ? 0 : (int)(blockIdx.x >> 7);
  const int h = lin & 7, b = (lin >> 3) & 3, qt = lin >> 5;

  const f16 qscale = (f16)0.18033688f;   // 0.125 * log2(e)
  f16x8 qf[QG][2];
  #pragma unroll
  for (int qg = 0; qg < QG; qg++) {
    const int qrow = qt * (64 * QG) + w * (16 * QG) + qg * 16 + lo4;
    const f16* Qp = Q + (size_t)(b * NQ + qrow) * qs + h * DH_ + hi2 * 8;
    qf[qg][0] = *(const f16x8*)(Qp);
    qf[qg][1] = *(const f16x8*)(Qp + 32);
    #pragma unroll
    for (int i = 0; i < 8; i++) { qf[qg][0][i] *= qscale; qf[qg][1][i] *= qscale; }
  }

  const int g2 = lo4 >> 2, j4 = lo4 & 3;
  const int kvp0 = 8 * g2 + j4;              // nf=0 (own block)
  const int kvp1 = 8 * (g2 ^ 2) + 4 + j4;    // nf=1 (partner block)
  const int pidx = (l ^ 32) << 2;            // bpermute partner index
  const int vswz = lo4 & 7;                  // V read swizzle

  const f16* Kb = Kp + ((size_t)b * S_ + c * CL) * kvs + h * DH_;
  const f16* VTbh = VT + (((size_t)(b * 8 + h)) << 17) + c * CL;

  float lsum[QG];
  f32x4 oacc[QG][4];
  #pragma unroll
  for (int qg = 0; qg < QG; qg++) {
    lsum[qg] = 0.f;
    #pragma unroll
    for (int df = 0; df < 4; df++) oacc[qg][df] = (f32x4){0.f, 0.f, 0.f, 0.f};
  }

  const int r0 = tid >> 3;   // K staging row 0..31
  const int c8 = tid & 7;    // staging 8-elem col chunk

  // prologue: stage tile 0
  #pragma unroll
  for (int i = 0; i < 2; i++) {
    int r = i * 32 + r0;
    GLDS16(VTbh + (size_t)r * 2048 + ((c8 ^ (r & 7)) * 8), &VtL[0][(i * 256 + tid) * 8]);
  }
  f16x8 kreg[2];
  #pragma unroll
  for (int i = 0; i < 2; i++)
    kreg[i] = *(const f16x8*)(Kb + (size_t)(i * 32 + r0) * kvs + c8 * 8);
  #pragma unroll
  for (int i = 0; i < 2; i++)
    *(f16x8*)(&Ks[0][i * 32 + r0][c8 * 8]) = kreg[i];
  __syncthreads();

  int cur = 0;
  for (int t = 0; t < NT; t++) {
    if (t + 1 < NT) {
      const int kt2 = (t + 1) * 64;
      #pragma unroll
      for (int i = 0; i < 2; i++) {
        int r = i * 32 + r0;
        GLDS16(VTbh + (size_t)r * 2048 + kt2 + ((c8 ^ (r & 7)) * 8),
               &VtL[cur ^ 1][(i * 256 + tid) * 8]);
      }
      #pragma unroll
      for (int i = 0; i < 2; i++)
        kreg[i] = *(const f16x8*)(Kb + (size_t)(kt2 + i * 32 + r0) * kvs + c8 * 8);
    }
    // S^T = K Q^T (log2 domain); K-fragments shared across q-groups
    f32x4 sacc[QG][4];
    #pragma unroll
    for (int nf = 0; nf < 4; nf++) {
      const int krow = ((nf & 1) ? kvp1 : kvp0) + (nf >> 1) * 32;
      f16x8 kf0 = *(const f16x8*)(&Ks[cur][krow][hi2 * 8]);
      f16x8 kf1 = *(const f16x8*)(&Ks[cur][krow][32 + hi2 * 8]);
      #pragma unroll
      for (int qg = 0; qg < QG; qg++) {
        f32x4 s = (f32x4){0.f, 0.f, 0.f, 0.f};
        s = MFMA16(kf0, qf[qg][0], s);
        s = MFMA16(kf1, qf[qg][1], s);
        sacc[qg][nf] = s;
      }
    }
    // p = exp2(s); per-lane partial row-sum; pack to f16 pairs
    uint32_t packs[QG][4][2];
    #pragma unroll
    for (int qg = 0; qg < QG; qg++)
      #pragma unroll
      for (int nf = 0; nf < 4; nf++) {
        float p0 = exp2f(sacc[qg][nf][0]);
        float p1 = exp2f(sacc[qg][nf][1]);
        float p2 = exp2f(sacc[qg][nf][2]);
        float p3 = exp2f(sacc[qg][nf][3]);
        lsum[qg] += (p0 + p1) + (p2 + p3);
        packs[qg][nf][0] = __builtin_bit_cast(uint32_t, __builtin_amdgcn_cvt_pkrtz(p0, p1));
        packs[qg][nf][1] = __builtin_bit_cast(uint32_t, __builtin_amdgcn_cvt_pkrtz(p2, p3));
      }
    // O^T += V^T P^T: V-fragments shared across q-groups
    #pragma unroll
    for (int ks = 0; ks < 2; ks++) {
      f16x8 pb[QG];
      #pragma unroll
      for (int qg = 0; qg < QG; qg++) {
        uint32_t w0 = packs[qg][2 * ks][0];
        uint32_t w1 = packs[qg][2 * ks][1];
        uint32_t w2 = (uint32_t)__builtin_amdgcn_ds_bpermute(pidx, (int)packs[qg][2 * ks + 1][0]);
        uint32_t w3 = (uint32_t)__builtin_amdgcn_ds_bpermute(pidx, (int)packs[qg][2 * ks + 1][1]);
        u32x4 bw = (u32x4){w0, w1, w2, w3};
        pb[qg] = __builtin_bit_cast(f16x8, bw);
      }
      #pragma unroll
      for (int df = 0; df < 4; df++) {
        const int r = df * 16 + lo4;
        const int cc = (ks * 4 + hi2) ^ vswz;
        f16x8 vf = *(const f16x8*)(&VtL[cur][r * 64 + cc * 8]);
        #pragma unroll
        for (int qg = 0; qg < QG; qg++)
          oacc[qg][df] = MFMA16(vf, pb[qg], oacc[qg][df]);
      }
    }
    if (t + 1 < NT) {
      #pragma unroll
      for (int i = 0; i < 2; i++)
        *(f16x8*)(&Ks[cur ^ 1][i * 32 + r0][c8 * 8]) = kreg[i];
    }
    __syncthreads();
    cur ^= 1;
  }

  #pragma unroll
  for (int qg = 0; qg < QG; qg++) {
    float r = lsum[qg];
    r += __shfl_xor(r, 16, 64);
    r += __shfl_xor(r, 32, 64);
    const int orow = qt * (64 * QG) + w * (16 * QG) + qg * 16 + lo4;
    if constexpr (CHUNKS == 1) {
      const float invl = 1.0f / r;
      f16* Ob = O + (size_t)(b * NQ + orow) * D_ + h * DH_ + hi2 * 4;
      #pragma unroll
      for (int df = 0; df < 4; df++) {
        f16 t4[4];
        #pragma unroll
        for (int j = 0; j < 4; j++) t4[j] = (f16)(oacc[qg][df][j] * invl);
        *(uint2*)(Ob + df * 16) = *(uint2*)t4;
      }
    } else {
      float* Op = Opart + ((size_t)c * NP_ + b * NQ + orow) * D_ + h * DH_ + hi2 * 4;
      #pragma unroll
      for (int df = 0; df < 4; df++) {
        float4 v = {oacc[qg][df][0], oacc[qg][df][1], oacc[qg][df][2], oacc[qg][df][3]};
        *(float4*)(Op + df * 16) = v;
      }
      if (hi2 == 0)
        Lpart[((size_t)c * NP_ + b * NQ + orow) * H_ + h] = r;
    }
  }
}

// ---------------------------------------------------------------------------
// combine split-KV partials: CO[row][col] = sum_c O_c / sum_c l_c
// ---------------------------------------------------------------------------
__global__ __launch_bounds__(128) void attn_reduce(
    const float* __restrict__ Opart, const float* __restrict__ Lpart,
    f16* __restrict__ CO)
{
  const int row = blockIdx.x;            // 0..NP_-1
  const int col = threadIdx.x * 4;
  const int h = col >> 6;
  float4 o = {0.f, 0.f, 0.f, 0.f};
  float ls = 0.f;
  #pragma unroll
  for (int c = 0; c < 4; c++) {
    const float4 v = *(const float4*)(Opart + ((size_t)c * NP_ + row) * D_ + col);
    o.x += v.x; o.y += v.y; o.z += v.z; o.w += v.w;
    ls += Lpart[((size_t)c * NP_ + row) * H_ + h];
  }
  const float inv = 1.0f / ls;
  f16 t4[4];
  t4[0] = (f16)(o.x * inv); t4[1] = (f16)(o.y * inv);
  t4[2] = (f16)(o.z * inv); t4[3] = (f16)(o.w * inv);
  *(uint2*)(CO + (size_t)row * D_ + col) = *(uint2*)t4;
}

// ---------------------------------------------------------------------------
// Fused residual + LayerNorm, all-f16 I/O (f32 math inside), 2 rows/block
// ---------------------------------------------------------------------------
__global__ __launch_bounds__(256) void ln_kernel(
    const f16* __restrict__ a, const f16* __restrict__ r,
    const float* __restrict__ g, const float* __restrict__ be,
    f16* __restrict__ out)
{
  const int row = blockIdx.x * 2 + (threadIdx.x >> 7);
  const int t = threadIdx.x & 127;
  const f16* ap = a + (size_t)row * D_ + t * 4;
  const f16* rp = r + (size_t)row * D_ + t * 4;
  uint2 au = *(const uint2*)ap, ru = *(const uint2*)rp;
  f16 a4[4], r4[4];
  *(uint2*)a4 = au; *(uint2*)r4 = ru;
  float x0 = (float)a4[0] + (float)r4[0];
  float x1 = (float)a4[1] + (float)r4[1];
  float x2 = (float)a4[2] + (float)r4[2];
  float x3 = (float)a4[3] + (float)r4[3];
  float sm = x0 + x1 + x2 + x3;
  float sq = x0*x0 + x1*x1 + x2*x2 + x3*x3;
  #pragma unroll
  for (int off = 32; off > 0; off >>= 1) {
    sm += __shfl_down(sm, off, 64);
    sq += __shfl_down(sq, off, 64);
  }
  __shared__ float s0[4], s1[4];
  if ((threadIdx.x & 63) == 0) { s0[threadIdx.x >> 6] = sm; s1[threadIdx.x >> 6] = sq; }
  __syncthreads();
  const int base = (threadIdx.x >> 7) * 2;
  const float Sm = s0[base] + s0[base + 1];
  const float Sq = s1[base] + s1[base + 1];
  const float mean = Sm * (1.0f / 512.0f);
  const float var  = Sq * (1.0f / 512.0f) - mean * mean;
  const float inv  = rsqrtf(var + 1e-5f);
  const float4 vg = *(const float4*)(g + t * 4);
  const float4 vb = *(const float4*)(be + t * 4);
  f16 o4[4];
  o4[0] = (f16)(vg.x * (x0 - mean) * inv + vb.x);
  o4[1] = (f16)(vg.y * (x1 - mean) * inv + vb.y);
  o4[2] = (f16)(vg.z * (x2 - mean) * inv + vb.z);
  o4[3] = (f16)(vg.w * (x3 - mean) * inv + vb.w);
  *(uint2*)(out + (size_t)row * D_ + t * 4) = *(uint2*)o4;
}

// ---------------------------------------------------------------------------
extern "C" void kernel_launch(void* const* d_in, const int* in_sizes, int n_in,
                              void* d_out, int out_size, void* d_ws, size_t ws_size,
                              hipStream_t stream) {
  const int*   bytes_seq = (const int*)  d_in[0];
  const int*   patch_idx = (const int*)  d_in[1];
  const float* byte_emb  = (const float*)d_in[2];
  const float* ngram_emb = (const float*)d_in[3];
  const float* sWq = (const float*)d_in[4];  const float* sbq = (const float*)d_in[5];
  const float* sWk = (const float*)d_in[6];  const float* sbk = (const float*)d_in[7];
  const float* sWv = (const float*)d_in[8];  const float* sbv = (const float*)d_in[9];
  const float* sWo = (const float*)d_in[10]; const float* sbo = (const float*)d_in[11];
  const float* ln1g = (const float*)d_in[12]; const float* ln1b = (const float*)d_in[13];
  const float* W1 = (const float*)d_in[14];  const float* b1 = (const float*)d_in[15];
  const float* W2 = (const float*)d_in[16];  const float* b2 = (const float*)d_in[17];
  const float* ln2g = (const float*)d_in[18]; const float* ln2b = (const float*)d_in[19];
  const float* cWq = (const float*)d_in[20]; const float* cbq = (const float*)d_in[21];
  const float* cWk = (const float*)d_in[22]; const float* cbk = (const float*)d_in[23];
  const float* cWv = (const float*)d_in[24]; const float* cbv = (const float*)d_in[25];
  const float* cWo = (const float*)d_in[26]; const float* cbo = (const float*)d_in[27];

  char* base = (char*)d_ws;
  const size_t MB = 1u << 20;
  f16* E16     = (f16*)(base + 0 * MB);       // 8 MB
  f16* TMP16   = (f16*)(base + 8 * MB);       // 8 MB
  f16* X116    = (f16*)(base + 16 * MB);      // 8 MB
  f16* X216    = (f16*)(base + 24 * MB);      // 8 MB
  f16* QKV16   = (f16*)(base + 32 * MB);      // [8192][1536] = 24 MB (V cols unused)
  f16* AT16    = (f16*)(base + 56 * MB);      // 8 MB
  f16* HID16   = (f16*)(base + 64 * MB);      // [8192][2048] = 32 MB
  f16* CKV16   = (f16*)(base + 96 * MB);      // [8192][1024] = 16 MB (V cols unused)
  f16* CQ16    = (f16*)(base + 112 * MB);     // 1 MB
  f16* CO16    = (f16*)(base + 113 * MB);     // 1 MB
  f16* WT      = (f16*)(base + 114 * MB);     // 8 MB transposed weights
  float* bqkv  = (float*)(base + 123 * MB);   // 1536 f32
  float* bckv  = bqkv + 1536;                 // 1024 f32
  f16* VT      = (f16*)(base + 124 * MB);     // [4][8][64][2048] = 8 MB (self V^T)
  f16* VT2     = (f16*)(base + 132 * MB);     // 8 MB (cross V^T)
  float* OPART = (float*)(base + 140 * MB);   // [4][1024][512] f32 = 8 MB
  float* LPART = (float*)(base + 148 * MB);   // [4][1024][8] f32 = 128 KB

  f16* QKVT = WT;                 // [1536][512]: Wq^T | Wk^T | Wv^T
  f16* sWoT = QKVT + 786432;
  f16* W1T  = sWoT + 262144;      // [2048][512]
  f16* W2T  = W1T + 1048576;      // [512][2048]
  f16* cWqT = W2T + 1048576;
  f16* CKVT = cWqT + 262144;      // [1024][512]: cWk^T | cWv^T
  f16* cWoT = CKVT + 524288;

  WJobs wj;
  {
    const float* wsrc[10] = {sWq, sWk, sWv, sWo, W1, W2, cWq, cWk, cWv, cWo};
    f16* wdst[10] = {QKVT, QKVT + 262144, QKVT + 524288, sWoT, W1T, W2T,
                     cWqT, CKVT, CKVT + 262144, cWoT};
    const int wK[10] = {512,512,512,512, 512,2048, 512,512,512,512};
    const int wN[10] = {512,512,512,512, 2048,512, 512,512,512,512};
    for (int i = 0; i < 10; i++) {
      wj.src[i] = wsrc[i]; wj.dst[i] = wdst[i];
      wj.K[i] = wK[i]; wj.N[i] = wN[i];
      wj.tiles[i] = (wK[i] >> 5) * (wN[i] >> 5);
    }
  }

  const dim3 blk256(256), blk128(128);

  prep_kernel<<<10240 + 10 + 4096, blk256, 0, stream>>>(
      wj, sbq, sbk, sbv, cbk, cbv, bqkv, bckv,
      bytes_seq, byte_emb, ngram_emb, E16);

  // fused QKV projection; V part straight to VT (per-head V^T)
  gemm_f16<f16, 0, 128, 1024, 512><<<dim3(64, 12), blk256, 0, stream>>>(
      E16, QKVT, bqkv, QKV16, 1536, nullptr, VT);

  // self-attention (128 q/block)
  attn_f16<2, 1><<<512, blk256, 0, stream>>>(
      QKV16, 1536, QKV16 + 512, 1536, VT, AT16, nullptr, nullptr, S_);

  // output projection + LN1
  gemm_f16<f16, 0, 64, -1, 512><<<dim3(64, 8), blk256, 0, stream>>>(
      AT16, sWoT, sbo, TMP16, 512, nullptr, nullptr);
  ln_kernel<<<N_/2, blk256, 0, stream>>>(E16, TMP16, ln1g, ln1b, X116);

  // FFN
  gemm_f16<f16, 1, 128, -1, 512><<<dim3(64, 16), blk256, 0, stream>>>(
      X116, W1T, b1, HID16, 2048, nullptr, nullptr);
  gemm_f16<f16, 0, 64, -1, 2048><<<dim3(64, 8), blk256, 0, stream>>>(
      HID16, W2T, b2, TMP16, 512, nullptr, nullptr);
  ln_kernel<<<N_/2, blk256, 0, stream>>>(X116, TMP16, ln2g, ln2b, X216);

  // cross: fused K|V projection (V^T to VT2) + gather-fused Q proj
  ckv_cq_kernel<<<576, blk256, 0, stream>>>(
      X216, CKVT, bckv, CKV16, VT2, cWqT, cbq, CQ16, patch_idx);
  // cross attention, split-KV x4 (flash-decode), then combine
  attn_f16<1, 4><<<512, blk256, 0, stream>>>(
      CQ16, 512, CKV16, 1024, VT2, nullptr, OPART, LPART, P_);
  attn_reduce<<<NP_, blk128, 0, stream>>>(OPART, LPART, CO16);

  // final projection: split-K x4 into OPART (reused), reduce+bias -> d_out
  co_splitk<<<dim3(8, 8, 4), blk256, 0, stream>>>(CO16, cWoT, OPART);
  co_reduce<<<NP_, blk128, 0, stream>>>(OPART, cbo, (float*)d_out);
}

// Round 11
// 276.417 us; speedup vs baseline: 1.0476x; 1.0032x over previous
//
#include <hip/hip_runtime.h>
#include <stdint.h>

#define B_   4
#define S_   2048
#define D_   512
#define H_   8
#define DH_  64
#define V_   100000
#define P_   256
#define N_   (B_*S_)    // 8192 rows
#define NP_  (B_*P_)    // 1024 rows

typedef _Float16 f16;
typedef _Float16 f16x8 __attribute__((ext_vector_type(8)));
typedef float    f32x4 __attribute__((ext_vector_type(4)));
typedef uint32_t u32x4 __attribute__((ext_vector_type(4)));

#define MFMA16(a,b,c) __builtin_amdgcn_mfma_f32_16x16x32_f16((a),(b),(c),0,0,0)
#define GLDS16(gp, lp) __builtin_amdgcn_global_load_lds( \
    (const __attribute__((address_space(1))) void*)(gp), \
    (__attribute__((address_space(3))) void*)(lp), 16, 0, 0)

// counted-vmcnt + raw barrier: wait until <=N VMEM ops outstanding (tile t
// complete, tile t+1 still in flight), THEN barrier -> every wave's tile-t
// GLDS writes are LDS-visible to all waves after the barrier.
template<int N>
__device__ __forceinline__ void wait_barrier() {
  if constexpr (N == 0)
    asm volatile("s_waitcnt vmcnt(0)\ns_barrier" ::: "memory");
  else if constexpr (N == 3)
    asm volatile("s_waitcnt vmcnt(3)\ns_barrier" ::: "memory");
  else
    asm volatile("s_waitcnt vmcnt(4)\ns_barrier" ::: "memory");
}

// ---------------------------------------------------------------------------
// Weight-conversion job table
// ---------------------------------------------------------------------------
struct WJobs {
  const float* src[10];
  f16* dst[10];
  int K[10], N[10], tiles[10];
};

// ---------------------------------------------------------------------------
// prep kernel: wconv (10240 blocks) + bias concat (10) + embed (4096, 2 rows)
// ---------------------------------------------------------------------------
__global__ __launch_bounds__(256) void prep_kernel(WJobs jobs,
    const float* __restrict__ sbq, const float* __restrict__ sbk,
    const float* __restrict__ sbv, const float* __restrict__ cbk,
    const float* __restrict__ cbv, float* __restrict__ bqkv,
    float* __restrict__ bckv,
    const int* __restrict__ bytes_seq, const float* __restrict__ byte_emb,
    const float* __restrict__ ngram_emb, f16* __restrict__ out16)
{
  int bid = blockIdx.x;
  if (bid < 10240) {
    // ---- weight transpose+cast: fp32 [K][N] -> f16 [N][K] ----
    const int j = bid >> 10, tile = bid & 1023;
    if (tile >= jobs.tiles[j]) return;
    const int K = jobs.K[j], N = jobs.N[j];
    const int ntiles = N >> 5;
    const int kt = (tile / ntiles) << 5, nt = (tile % ntiles) << 5;
    __shared__ float T[32][33];
    const int t = threadIdx.x;
    const float* src = jobs.src[j];
    #pragma unroll
    for (int p = 0; p < 4; p++) {
      int lin = t + p * 256;
      int rr = lin >> 5, cc = lin & 31;
      T[rr][cc] = src[(size_t)(kt + rr) * N + nt + cc];
    }
    __syncthreads();
    f16* dst = jobs.dst[j];
    #pragma unroll
    for (int p = 0; p < 4; p++) {
      int lin = t + p * 256;
      int rr = lin >> 5, cc = lin & 31;
      dst[(size_t)(nt + rr) * K + kt + cc] = (f16)T[cc][rr];
    }
    return;
  }
  bid -= 10240;
  if (bid < 10) {
    // ---- bias concat ----
    int t = bid * 256 + threadIdx.x;
    if (t < 512)       bqkv[t] = sbq[t];
    else if (t < 1024) bqkv[t] = sbk[t - 512];
    else if (t < 1536) bqkv[t] = sbv[t - 1024];
    else if (t < 2048) bckv[t - 1536] = cbk[t - 1536];
    else if (t < 2560) bckv[t - 1536] = cbv[t - 2048];
    return;
  }
  bid -= 10;
  // ---- embedding + n-gram hash (2 rows per block) ----
  const int pos = bid * 2 + (threadIdx.x >> 7);
  const int b = pos / S_, s = pos % S_;
  const int* bs = bytes_seq + (size_t)b * S_;

  int w[8];
  #pragma unroll
  for (int k = 0; k < 8; k++) {
    int p = s - 7 + k;
    w[k] = (p >= 0) ? bs[p] : 0;
  }
  int idx[6];
  #pragma unroll
  for (int j = 0; j < 6; j++) {
    const int n = j + 3;
    int id = 0;
    if (s >= n - 1) {
      uint64_t h = 0;
      for (int k = 0; k < n; k++)
        h += (uint64_t)(uint32_t)w[8 - n + k] << (8 * k);
      long long sh = (long long)h;       // int64 wraparound semantics
      long long r = sh % (long long)V_;  // trunc-mod to floor-mod
      if (r < 0) r += V_;
      id = (int)r;
    }
    idx[j] = id;
  }
  const int d = (threadIdx.x & 127) * 4;
  float4 acc = *(const float4*)(byte_emb + (size_t)bs[s] * D_ + d);
  #pragma unroll
  for (int j = 0; j < 6; j++) {
    const float4 v = *(const float4*)(ngram_emb + ((size_t)j * V_ + idx[j]) * D_ + d);
    acc.x += v.x; acc.y += v.y; acc.z += v.z; acc.w += v.w;
  }
  const float inv7 = 1.0f / 7.0f;
  f16 t4[4];
  t4[0] = (f16)(acc.x * inv7); t4[1] = (f16)(acc.y * inv7);
  t4[2] = (f16)(acc.z * inv7); t4[3] = (f16)(acc.w * inv7);
  *(uint2*)(out16 + (size_t)pos * D_ + d) = *(uint2*)t4;
}

// ---------------------------------------------------------------------------
// f16 MFMA GEMM body (C^T accumulation), TRIPLE-buffered LDS with counted
// vmcnt across raw barriers (T4): stage 2 tiles ahead; at each K-step wait
// only until the CURRENT tile's loads are done (next tile's stay in flight).
// 128xBN tile, BK=32, 4 waves, K compile-time.
// rowmap: A row r -> (r>>8)*S_ + rowmap[r] (patch gather fused).
// VTSTART>=0: cols >= VTSTART go to vt in [b][h][dh][s] layout (per-head V^T).
// bias may be nullptr (split-K partials; bias added in reduce).
// ---------------------------------------------------------------------------
template<typename OutT, int RELU, int BN, int VTSTART, int K>
__device__ __forceinline__ void gemm_body(
    const f16* __restrict__ A, const f16* __restrict__ Bt,
    const float* __restrict__ bias, OutT* __restrict__ C,
    int N, const int* __restrict__ rowmap,
    f16* __restrict__ vt, int bmi, int bni, int lda, int ldb)
{
  constexpr int NF = BN / 32;           // N-frags per wave
  constexpr int NT = K / 32;            // K-steps
  constexpr int GL = 2 + BN / 64;       // GLDS per thread per tile
  __shared__ __align__(16) f16 As[3][128 * 32];
  __shared__ __align__(16) f16 Bs[3][BN * 32];
  const int tid = threadIdx.x;
  const int l = tid & 63;
  const int lo4 = l & 15, hi2 = l >> 4;
  const int w = tid >> 6;
  const int wr = w >> 1, wc = w & 1;
  const int bm = bmi * 128, bn = bni * BN;

  const f16* ap[2];
  #pragma unroll
  for (int i = 0; i < 2; i++) {
    int r = bm + i * 64 + (tid >> 2);
    int ar = rowmap ? ((r >> 8) * S_ + rowmap[r]) : r;
    ap[i] = A + (size_t)ar * lda + (tid & 3) * 8;
  }
  const f16* bp[BN / 64];
  #pragma unroll
  for (int i = 0; i < BN / 64; i++) {
    int c = i * 256 + tid;
    bp[i] = Bt + (size_t)(bn + (c >> 2)) * ldb + (tid & 3) * 8;
  }

  f32x4 acc[4][NF];
  #pragma unroll
  for (int m = 0; m < 4; m++)
    #pragma unroll
    for (int n = 0; n < NF; n++) acc[m][n] = (f32x4){0.f, 0.f, 0.f, 0.f};

  // prologue: stage tiles 0 and 1
  #pragma unroll
  for (int i = 0; i < 2; i++)
    GLDS16(ap[i], &As[0][(i * 256 + tid) * 8]);
  #pragma unroll
  for (int i = 0; i < BN / 64; i++)
    GLDS16(bp[i], &Bs[0][(i * 256 + tid) * 8]);
  #pragma unroll
  for (int i = 0; i < 2; i++)
    GLDS16(ap[i] + 32, &As[1][(i * 256 + tid) * 8]);
  #pragma unroll
  for (int i = 0; i < BN / 64; i++)
    GLDS16(bp[i] + 32, &Bs[1][(i * 256 + tid) * 8]);

  auto do_mma = [&](int c) {
    f16x8 af[4], bf[NF];
    const f16* pa = &As[c][(wr * 64 + lo4) * 32 + hi2 * 8];
    const f16* pb = &Bs[c][(wc * (BN / 2) + lo4) * 32 + hi2 * 8];
    #pragma unroll
    for (int m = 0; m < 4; m++) af[m] = *(const f16x8*)(pa + m * 16 * 32);
    #pragma unroll
    for (int n = 0; n < NF; n++) bf[n] = *(const f16x8*)(pb + n * 16 * 32);
    #pragma unroll
    for (int m = 0; m < 4; m++)
      #pragma unroll
      for (int n = 0; n < NF; n++)
        acc[m][n] = MFMA16(bf[n], af[m], acc[m][n]);   // C^T: swap operands
  };

  int cur = 0;
  #pragma unroll 3
  for (int t = 0; t < NT - 1; ++t) {
    wait_barrier<GL>();                  // tile t ready; tile t+1 in flight
    if (t + 2 < NT) {
      const int k0 = (t + 2) << 5;
      int stg = cur + 2; if (stg >= 3) stg -= 3;   // buffer freed by barrier
      #pragma unroll
      for (int i = 0; i < 2; i++)
        GLDS16(ap[i] + k0, &As[stg][(i * 256 + tid) * 8]);
      #pragma unroll
      for (int i = 0; i < BN / 64; i++)
        GLDS16(bp[i] + k0, &Bs[stg][(i * 256 + tid) * 8]);
    }
    do_mma(cur);
    cur = (cur == 2) ? 0 : cur + 1;
  }
  wait_barrier<0>();                     // final tile: full drain
  do_mma(cur);

  // SWAPPED C/D layout: product row = C-col = n*16 + hi2*4 + j,
  //                     product col = C-row = m*16 + lo4.
  if constexpr (VTSTART >= 0) {
    if (bn >= VTSTART) {
      // V^T epilogue: vt[((b*8+h)*64+d)*2048 + s]; scalar stores (d varies j)
      #pragma unroll
      for (int n = 0; n < NF; n++) {
        const int col0 = bn + wc * (BN / 2) + n * 16 + hi2 * 4;
        float bb[4] = {0.f, 0.f, 0.f, 0.f};
        if (bias) *(float4*)bb = *(const float4*)(bias + col0);
        #pragma unroll
        for (int m = 0; m < 4; m++) {
          const int s = bm + wr * 64 + m * 16 + lo4;
          #pragma unroll
          for (int j = 0; j < 4; j++) {
            const int dcol = col0 + j - VTSTART;
            vt[(((size_t)(s >> 11) * 8 + (dcol >> 6)) << 17) +
               ((size_t)(dcol & 63) << 11) + (s & 2047)] =
                (f16)(acc[m][n][j] + bb[j]);
          }
        }
      }
      return;
    }
  }

  #pragma unroll
  for (int n = 0; n < NF; n++) {
    const int col0 = bn + wc * (BN / 2) + n * 16 + hi2 * 4;
    float bb[4] = {0.f, 0.f, 0.f, 0.f};
    if (bias) *(float4*)bb = *(const float4*)(bias + col0);
    #pragma unroll
    for (int m = 0; m < 4; m++) {
      const int row = bm + wr * 64 + m * 16 + lo4;
      float v[4];
      #pragma unroll
      for (int j = 0; j < 4; j++) {
        v[j] = acc[m][n][j] + bb[j];
        if (RELU) v[j] = fmaxf(v[j], 0.f);
      }
      if constexpr (sizeof(OutT) == 2) {
        f16 t4[4];
        #pragma unroll
        for (int j = 0; j < 4; j++) t4[j] = (f16)v[j];
        *(uint2*)((f16*)C + (size_t)row * N + col0) = *(uint2*)t4;
      } else {
        float4 t4 = {v[0], v[1], v[2], v[3]};
        *(float4*)((float*)C + (size_t)row * N + col0) = t4;
      }
    }
  }
}

template<typename OutT, int RELU, int BN, int VTSTART, int K>
__global__ __launch_bounds__(256) void gemm_f16(
    const f16* __restrict__ A, const f16* __restrict__ Bt,
    const float* __restrict__ bias, OutT* __restrict__ C,
    int N, const int* __restrict__ rowmap, f16* __restrict__ vt)
{
  gemm_body<OutT, RELU, BN, VTSTART, K>(A, Bt, bias, C, N, rowmap, vt,
                                        blockIdx.x, blockIdx.y, K, K);
}

// ---------------------------------------------------------------------------
// merged cKV GEMM (512 blocks, V^T out) + gather-fused cQ GEMM (64 blocks)
// ---------------------------------------------------------------------------
__global__ __launch_bounds__(256) void ckv_cq_kernel(
    const f16* __restrict__ X, const f16* __restrict__ CKVT,
    const float* __restrict__ bckv, f16* __restrict__ CKV,
    f16* __restrict__ vt2, const f16* __restrict__ cWqT,
    const float* __restrict__ cbq, f16* __restrict__ CQ,
    const int* __restrict__ pidx)
{
  int bid = blockIdx.x;
  if (bid < 512) {
    gemm_body<f16, 0, 128, 512, 512>(X, CKVT, bckv, CKV, 1024,
                                     nullptr, vt2, bid >> 3, bid & 7, 512, 512);
  } else {
    bid -= 512;
    gemm_body<f16, 0, 64, -1, 512>(X, cWqT, cbq, CQ, 512,
                                   pidx, nullptr, bid >> 3, bid & 7, 512, 512);
  }
}

// ---------------------------------------------------------------------------
// final projection, split-K x4: partial[z] = CO[:, z*128:(z+1)*128] @ W-chunk
// ---------------------------------------------------------------------------
__global__ __launch_bounds__(256) void co_splitk(
    const f16* __restrict__ A, const f16* __restrict__ Bt,
    float* __restrict__ part)
{
  const int z = blockIdx.z;
  gemm_body<float, 0, 64, -1, 128>(A + z * 128, Bt + z * 128, nullptr,
      part + (size_t)z * NP_ * 512, 512, nullptr, nullptr,
      blockIdx.x, blockIdx.y, 512, 512);
}

__global__ __launch_bounds__(128) void co_reduce(
    const float* __restrict__ part, const float* __restrict__ bias,
    float* __restrict__ out)
{
  const int row = blockIdx.x;
  const int col = threadIdx.x * 4;
  float4 s = *(const float4*)(bias + col);
  #pragma unroll
  for (int c = 0; c < 4; c++) {
    const float4 v = *(const float4*)(part + ((size_t)c * NP_ + row) * 512 + col);
    s.x += v.x; s.y += v.y; s.z += v.z; s.w += v.w;
  }
  *(float4*)(out + (size_t)row * 512 + col) = s;
}

// ---------------------------------------------------------------------------
// f16 MFMA flash attention, max-free softmax (p = exp2(s)), swapped QK^T with
// permuted K-rows; P in registers via cvt_pkrtz + ds_bpermute. QG q-groups.
// CHUNKS>1: flash-decode split-KV, unnormalized f32 partials + lsum.
// V pre-transposed in global (VT[b][h][d][s]); staged to linear LDS via
// GLDS with XOR-swizzled global source; read with matching swizzle.
// ---------------------------------------------------------------------------
template<int QG, int CHUNKS>
__global__ __launch_bounds__(256) void attn_f16(
    const f16* __restrict__ Q, int qs,
    const f16* __restrict__ Kp, int kvs,
    const f16* __restrict__ VT, f16* __restrict__ O,
    float* __restrict__ Opart, float* __restrict__ Lpart, int NQ)
{
  constexpr int CL = S_ / CHUNKS;      // kv chunk length
  constexpr int NT = CL / 64;
  __shared__ __align__(16) f16 Ks[2][64][76];
  __shared__ __align__(16) f16 VtL[2][64 * 64];

  const int tid = threadIdx.x;
  const int w = tid >> 6, l = tid & 63;
  const int lo4 = l & 15, hi2 = l >> 4;
  const int lin = (CHUNKS == 1) ? blockIdx.x : (blockIdx.x & 127);
  const int c   = (CHUNKS == 1) ? 0 : (int)(blockIdx.x >> 7);
  const int h = lin & 7, b = (lin >> 3) & 3, qt = lin >> 5;

  const f16 qscale = (f16)0.18033688f;   // 0.125 * log2(e)
  f16x8 qf[QG][2];
  #pragma unroll
  for (int qg = 0; qg < QG; qg++) {
    const int qrow = qt * (64 * QG) + w * (16 * QG) + qg * 16 + lo4;
    const f16* Qp = Q + (size_t)(b * NQ + qrow) * qs + h * DH_ + hi2 * 8;
    qf[qg][0] = *(const f16x8*)(Qp);
    qf[qg][1] = *(const f16x8*)(Qp + 32);
    #pragma unroll
    for (int i = 0; i < 8; i++) { qf[qg][0][i] *= qscale; qf[qg][1][i] *= qscale; }
  }

  const int g2 = lo4 >> 2, j4 = lo4 & 3;
  const int kvp0 = 8 * g2 + j4;              // nf=0 (own block)
  const int kvp1 = 8 * (g2 ^ 2) + 4 + j4;    // nf=1 (partner block)
  const int pidx = (l ^ 32) << 2;            // bpermute partner index
  const int vswz = lo4 & 7;                  // V read swizzle

  const f16* Kb = Kp + ((size_t)b * S_ + c * CL) * kvs + h * DH_;
  const f16* VTbh = VT + (((size_t)(b * 8 + h)) << 17) + c * CL;

  float lsum[QG];
  f32x4 oacc[QG][4];
  #pragma unroll
  for (int qg = 0; qg < QG; qg++) {
    lsum[qg] = 0.f;
    #pragma unroll
    for (int df = 0; df < 4; df++) oacc[qg][df] = (f32x4){0.f, 0.f, 0.f, 0.f};
  }

  const int r0 = tid >> 3;   // K staging row 0..31
  const int c8 = tid & 7;    // staging 8-elem col chunk

  // prologue: stage tile 0
  #pragma unroll
  for (int i = 0; i < 2; i++) {
    int r = i * 32 + r0;
    GLDS16(VTbh + (size_t)r * 2048 + ((c8 ^ (r & 7)) * 8), &VtL[0][(i * 256 + tid) * 8]);
  }
  f16x8 kreg[2];
  #pragma unroll
  for (int i = 0; i < 2; i++)
    kreg[i] = *(const f16x8*)(Kb + (size_t)(i * 32 + r0) * kvs + c8 * 8);
  #pragma unroll
  for (int i = 0; i < 2; i++)
    *(f16x8*)(&Ks[0][i * 32 + r0][c8 * 8]) = kreg[i];
  __syncthreads();

  int cur = 0;
  for (int t = 0; t < NT; t++) {
    if (t + 1 < NT) {
      const int kt2 = (t + 1) * 64;
      #pragma unroll
      for (int i = 0; i < 2; i++) {
        int r = i * 32 + r0;
        GLDS16(VTbh + (size_t)r * 2048 + kt2 + ((c8 ^ (r & 7)) * 8),
               &VtL[cur ^ 1][(i * 256 + tid) * 8]);
      }
      #pragma unroll
      for (int i = 0; i < 2; i++)
        kreg[i] = *(const f16x8*)(Kb + (size_t)(kt2 + i * 32 + r0) * kvs + c8 * 8);
    }
    // S^T = K Q^T (log2 domain); K-fragments shared across q-groups
    f32x4 sacc[QG][4];
    #pragma unroll
    for (int nf = 0; nf < 4; nf++) {
      const int krow = ((nf & 1) ? kvp1 : kvp0) + (nf >> 1) * 32;
      f16x8 kf0 = *(const f16x8*)(&Ks[cur][krow][hi2 * 8]);
      f16x8 kf1 = *(const f16x8*)(&Ks[cur][krow][32 + hi2 * 8]);
      #pragma unroll
      for (int qg = 0; qg < QG; qg++) {
        f32x4 s = (f32x4){0.f, 0.f, 0.f, 0.f};
        s = MFMA16(kf0, qf[qg][0], s);
        s = MFMA16(kf1, qf[qg][1], s);
        sacc[qg][nf] = s;
      }
    }
    // p = exp2(s); per-lane partial row-sum; pack to f16 pairs
    uint32_t packs[QG][4][2];
    #pragma unroll
    for (int qg = 0; qg < QG; qg++)
      #pragma unroll
      for (int nf = 0; nf < 4; nf++) {
        float p0 = exp2f(sacc[qg][nf][0]);
        float p1 = exp2f(sacc[qg][nf][1]);
        float p2 = exp2f(sacc[qg][nf][2]);
        float p3 = exp2f(sacc[qg][nf][3]);
        lsum[qg] += (p0 + p1) + (p2 + p3);
        packs[qg][nf][0] = __builtin_bit_cast(uint32_t, __builtin_amdgcn_cvt_pkrtz(p0, p1));
        packs[qg][nf][1] = __builtin_bit_cast(uint32_t, __builtin_amdgcn_cvt_pkrtz(p2, p3));
      }
    // O^T += V^T P^T: V-fragments shared across q-groups
    #pragma unroll
    for (int ks = 0; ks < 2; ks++) {
      f16x8 pb[QG];
      #pragma unroll
      for (int qg = 0; qg < QG; qg++) {
        uint32_t w0 = packs[qg][2 * ks][0];
        uint32_t w1 = packs[qg][2 * ks][1];
        uint32_t w2 = (uint32_t)__builtin_amdgcn_ds_bpermute(pidx, (int)packs[qg][2 * ks + 1][0]);
        uint32_t w3 = (uint32_t)__builtin_amdgcn_ds_bpermute(pidx, (int)packs[qg][2 * ks + 1][1]);
        u32x4 bw = (u32x4){w0, w1, w2, w3};
        pb[qg] = __builtin_bit_cast(f16x8, bw);
      }
      #pragma unroll
      for (int df = 0; df < 4; df++) {
        const int r = df * 16 + lo4;
        const int cc = (ks * 4 + hi2) ^ vswz;
        f16x8 vf = *(const f16x8*)(&VtL[cur][r * 64 + cc * 8]);
        #pragma unroll
        for (int qg = 0; qg < QG; qg++)
          oacc[qg][df] = MFMA16(vf, pb[qg], oacc[qg][df]);
      }
    }
    if (t + 1 < NT) {
      #pragma unroll
      for (int i = 0; i < 2; i++)
        *(f16x8*)(&Ks[cur ^ 1][i * 32 + r0][c8 * 8]) = kreg[i];
    }
    __syncthreads();
    cur ^= 1;
  }

  #pragma unroll
  for (int qg = 0; qg < QG; qg++) {
    float r = lsum[qg];
    r += __shfl_xor(r, 16, 64);
    r += __shfl_xor(r, 32, 64);
    const int orow = qt * (64 * QG) + w * (16 * QG) + qg * 16 + lo4;
    if constexpr (CHUNKS == 1) {
      const float invl = 1.0f / r;
      f16* Ob = O + (size_t)(b * NQ + orow) * D_ + h * DH_ + hi2 * 4;
      #pragma unroll
      for (int df = 0; df < 4; df++) {
        f16 t4[4];
        #pragma unroll
        for (int j = 0; j < 4; j++) t4[j] = (f16)(oacc[qg][df][j] * invl);
        *(uint2*)(Ob + df * 16) = *(uint2*)t4;
      }
    } else {
      float* Op = Opart + ((size_t)c * NP_ + b * NQ + orow) * D_ + h * DH_ + hi2 * 4;
      #pragma unroll
      for (int df = 0; df < 4; df++) {
        float4 v = {oacc[qg][df][0], oacc[qg][df][1], oacc[qg][df][2], oacc[qg][df][3]};
        *(float4*)(Op + df * 16) = v;
      }
      if (hi2 == 0)
        Lpart[((size_t)c * NP_ + b * NQ + orow) * H_ + h] = r;
    }
  }
}

// ---------------------------------------------------------------------------
// combine split-KV partials: CO[row][col] = sum_c O_c / sum_c l_c
// ---------------------------------------------------------------------------
__global__ __launch_bounds__(128) void attn_reduce(
    const float* __restrict__ Opart, const float* __restrict__ Lpart,
    f16* __restrict__ CO)
{
  const int row = blockIdx.x;            // 0..NP_-1
  const int col = threadIdx.x * 4;
  const int h = col >> 6;
  float4 o = {0.f, 0.f, 0.f, 0.f};
  float ls = 0.f;
  #pragma unroll
  for (int c = 0; c < 4; c++) {
    const float4 v = *(const float4*)(Opart + ((size_t)c * NP_ + row) * D_ + col);
    o.x += v.x; o.y += v.y; o.z += v.z; o.w += v.w;
    ls += Lpart[((size_t)c * NP_ + row) * H_ + h];
  }
  const float inv = 1.0f / ls;
  f16 t4[4];
  t4[0] = (f16)(o.x * inv); t4[1] = (f16)(o.y * inv);
  t4[2] = (f16)(o.z * inv); t4[3] = (f16)(o.w * inv);
  *(uint2*)(CO + (size_t)row * D_ + col) = *(uint2*)t4;
}

// ---------------------------------------------------------------------------
// Fused residual + LayerNorm, all-f16 I/O (f32 math inside), 2 rows/block
// ---------------------------------------------------------------------------
__global__ __launch_bounds__(256) void ln_kernel(
    const f16* __restrict__ a, const f16* __restrict__ r,
    const float* __restrict__ g, const float* __restrict__ be,
    f16* __restrict__ out)
{
  const int row = blockIdx.x * 2 + (threadIdx.x >> 7);
  const int t = threadIdx.x & 127;
  const f16* ap = a + (size_t)row * D_ + t * 4;
  const f16* rp = r + (size_t)row * D_ + t * 4;
  uint2 au = *(const uint2*)ap, ru = *(const uint2*)rp;
  f16 a4[4], r4[4];
  *(uint2*)a4 = au; *(uint2*)r4 = ru;
  float x0 = (float)a4[0] + (float)r4[0];
  float x1 = (float)a4[1] + (float)r4[1];
  float x2 = (float)a4[2] + (float)r4[2];
  float x3 = (float)a4[3] + (float)r4[3];
  float sm = x0 + x1 + x2 + x3;
  float sq = x0*x0 + x1*x1 + x2*x2 + x3*x3;
  #pragma unroll
  for (int off = 32; off > 0; off >>= 1) {
    sm += __shfl_down(sm, off, 64);
    sq += __shfl_down(sq, off, 64);
  }
  __shared__ float s0[4], s1[4];
  if ((threadIdx.x & 63) == 0) { s0[threadIdx.x >> 6] = sm; s1[threadIdx.x >> 6] = sq; }
  __syncthreads();
  const int base = (threadIdx.x >> 7) * 2;
  const float Sm = s0[base] + s0[base + 1];
  const float Sq = s1[base] + s1[base + 1];
  const float mean = Sm * (1.0f / 512.0f);
  const float var  = Sq * (1.0f / 512.0f) - mean * mean;
  const float inv  = rsqrtf(var + 1e-5f);
  const float4 vg = *(const float4*)(g + t * 4);
  const float4 vb = *(const float4*)(be + t * 4);
  f16 o4[4];
  o4[0] = (f16)(vg.x * (x0 - mean) * inv + vb.x);
  o4[1] = (f16)(vg.y * (x1 - mean) * inv + vb.y);
  o4[2] = (f16)(vg.z * (x2 - mean) * inv + vb.z);
  o4[3] = (f16)(vg.w * (x3 - mean) * inv + vb.w);
  *(uint2*)(out + (size_t)row * D_ + t * 4) = *(uint2*)o4;
}

// ---------------------------------------------------------------------------
extern "C" void kernel_launch(void* const* d_in, const int* in_sizes, int n_in,
                              void* d_out, int out_size, void* d_ws, size_t ws_size,
                              hipStream_t stream) {
  const int*   bytes_seq = (const int*)  d_in[0];
  const int*   patch_idx = (const int*)  d_in[1];
  const float* byte_emb  = (const float*)d_in[2];
  const float* ngram_emb = (const float*)d_in[3];
  const float* sWq = (const float*)d_in[4];  const float* sbq = (const float*)d_in[5];
  const float* sWk = (const float*)d_in[6];  const float* sbk = (const float*)d_in[7];
  const float* sWv = (const float*)d_in[8];  const float* sbv = (const float*)d_in[9];
  const float* sWo = (const float*)d_in[10]; const float* sbo = (const float*)d_in[11];
  const float* ln1g = (const float*)d_in[12]; const float* ln1b = (const float*)d_in[13];
  const float* W1 = (const float*)d_in[14];  const float* b1 = (const float*)d_in[15];
  const float* W2 = (const float*)d_in[16];  const float* b2 = (const float*)d_in[17];
  const float* ln2g = (const float*)d_in[18]; const float* ln2b = (const float*)d_in[19];
  const float* cWq = (const float*)d_in[20]; const float* cbq = (const float*)d_in[21];
  const float* cWk = (const float*)d_in[22]; const float* cbk = (const float*)d_in[23];
  const float* cWv = (const float*)d_in[24]; const float* cbv = (const float*)d_in[25];
  const float* cWo = (const float*)d_in[26]; const float* cbo = (const float*)d_in[27];

  char* base = (char*)d_ws;
  const size_t MB = 1u << 20;
  f16* E16     = (f16*)(base + 0 * MB);       // 8 MB
  f16* TMP16   = (f16*)(base + 8 * MB);       // 8 MB
  f16* X116    = (f16*)(base + 16 * MB);      // 8 MB
  f16* X216    = (f16*)(base + 24 * MB);      // 8 MB
  f16* QKV16   = (f16*)(base + 32 * MB);      // [8192][1536] = 24 MB (V cols unused)
  f16* AT16    = (f16*)(base + 56 * MB);      // 8 MB
  f16* HID16   = (f16*)(base + 64 * MB);      // [8192][2048] = 32 MB
  f16* CKV16   = (f16*)(base + 96 * MB);      // [8192][1024] = 16 MB (V cols unused)
  f16* CQ16    = (f16*)(base + 112 * MB);     // 1 MB
  f16* CO16    = (f16*)(base + 113 * MB);     // 1 MB
  f16* WT      = (f16*)(base + 114 * MB);     // 8 MB transposed weights
  float* bqkv  = (float*)(base + 123 * MB);   // 1536 f32
  float* bckv  = bqkv + 1536;                 // 1024 f32
  f16* VT      = (f16*)(base + 124 * MB);     // [4][8][64][2048] = 8 MB (self V^T)
  f16* VT2     = (f16*)(base + 132 * MB);     // 8 MB (cross V^T)
  float* OPART = (float*)(base + 140 * MB);   // [4][1024][512] f32 = 8 MB
  float* LPART = (float*)(base + 148 * MB);   // [4][1024][8] f32 = 128 KB

  f16* QKVT = WT;                 // [1536][512]: Wq^T | Wk^T | Wv^T
  f16* sWoT = QKVT + 786432;
  f16* W1T  = sWoT + 262144;      // [2048][512]
  f16* W2T  = W1T + 1048576;      // [512][2048]
  f16* cWqT = W2T + 1048576;
  f16* CKVT = cWqT + 262144;      // [1024][512]: cWk^T | cWv^T
  f16* cWoT = CKVT + 524288;

  WJobs wj;
  {
    const float* wsrc[10] = {sWq, sWk, sWv, sWo, W1, W2, cWq, cWk, cWv, cWo};
    f16* wdst[10] = {QKVT, QKVT + 262144, QKVT + 524288, sWoT, W1T, W2T,
                     cWqT, CKVT, CKVT + 262144, cWoT};
    const int wK[10] = {512,512,512,512, 512,2048, 512,512,512,512};
    const int wN[10] = {512,512,512,512, 2048,512, 512,512,512,512};
    for (int i = 0; i < 10; i++) {
      wj.src[i] = wsrc[i]; wj.dst[i] = wdst[i];
      wj.K[i] = wK[i]; wj.N[i] = wN[i];
      wj.tiles[i] = (wK[i] >> 5) * (wN[i] >> 5);
    }
  }

  const dim3 blk256(256), blk128(128);

  prep_kernel<<<10240 + 10 + 4096, blk256, 0, stream>>>(
      wj, sbq, sbk, sbv, cbk, cbv, bqkv, bckv,
      bytes_seq, byte_emb, ngram_emb, E16);

  // fused QKV projection; V part straight to VT (per-head V^T)
  gemm_f16<f16, 0, 128, 1024, 512><<<dim3(64, 12), blk256, 0, stream>>>(
      E16, QKVT, bqkv, QKV16, 1536, nullptr, VT);

  // self-attention (128 q/block)
  attn_f16<2, 1><<<512, blk256, 0, stream>>>(
      QKV16, 1536, QKV16 + 512, 1536, VT, AT16, nullptr, nullptr, S_);

  // output projection + LN1
  gemm_f16<f16, 0, 64, -1, 512><<<dim3(64, 8), blk256, 0, stream>>>(
      AT16, sWoT, sbo, TMP16, 512, nullptr, nullptr);
  ln_kernel<<<N_/2, blk256, 0, stream>>>(E16, TMP16, ln1g, ln1b, X116);

  // FFN
  gemm_f16<f16, 1, 128, -1, 512><<<dim3(64, 16), blk256, 0, stream>>>(
      X116, W1T, b1, HID16, 2048, nullptr, nullptr);
  gemm_f16<f16, 0, 64, -1, 2048><<<dim3(64, 8), blk256, 0, stream>>>(
      HID16, W2T, b2, TMP16, 512, nullptr, nullptr);
  ln_kernel<<<N_/2, blk256, 0, stream>>>(X116, TMP16, ln2g, ln2b, X216);

  // cross: fused K|V projection (V^T to VT2) + gather-fused Q proj
  ckv_cq_kernel<<<576, blk256, 0, stream>>>(
      X216, CKVT, bckv, CKV16, VT2, cWqT, cbq, CQ16, patch_idx);
  // cross attention, split-KV x4 (flash-decode), then combine
  attn_f16<1, 4><<<512, blk256, 0, stream>>>(
      CQ16, 512, CKV16, 1024, VT2, nullptr, OPART, LPART, P_);
  attn_reduce<<<NP_, blk128, 0, stream>>>(OPART, LPART, CO16);

  // final projection: split-K x4 into OPART (reused), reduce+bias -> d_out
  co_splitk<<<dim3(8, 8, 4), blk256, 0, stream>>>(CO16, cWoT, OPART);
  co_reduce<<<NP_, blk128, 0, stream>>>(OPART, cbo, (float*)d_out);
}

// Round 12
// 274.971 us; speedup vs baseline: 1.0532x; 1.0053x over previous
//
#include <hip/hip_runtime.h>
#include <stdint.h>

#define B_   4
#define S_   2048
#define D_   512
#define H_   8
#define DH_  64
#define V_   100000
#define P_   256
#define N_   (B_*S_)    // 8192 rows
#define NP_  (B_*P_)    // 1024 rows

typedef _Float16 f16;
typedef _Float16 f16x8 __attribute__((ext_vector_type(8)));
typedef float    f32x4 __attribute__((ext_vector_type(4)));
typedef uint32_t u32x4 __attribute__((ext_vector_type(4)));

#define MFMA16(a,b,c) __builtin_amdgcn_mfma_f32_16x16x32_f16((a),(b),(c),0,0,0)
#define GLDS16(gp, lp) __builtin_amdgcn_global_load_lds( \
    (const __attribute__((address_space(1))) void*)(gp), \
    (__attribute__((address_space(3))) void*)(lp), 16, 0, 0)

// counted-vmcnt + raw barrier: wait until <=N VMEM ops outstanding (tile t
// complete, tile t+1 still in flight), THEN barrier.
template<int N>
__device__ __forceinline__ void wait_barrier() {
  if constexpr (N == 0)
    asm volatile("s_waitcnt vmcnt(0)\ns_barrier" ::: "memory");
  else if constexpr (N == 3)
    asm volatile("s_waitcnt vmcnt(3)\ns_barrier" ::: "memory");
  else
    asm volatile("s_waitcnt vmcnt(4)\ns_barrier" ::: "memory");
}

// ---------------------------------------------------------------------------
// Weight-conversion job table
// ---------------------------------------------------------------------------
struct WJobs {
  const float* src[10];
  f16* dst[10];
  int K[10], N[10], tiles[10];
};

// ---------------------------------------------------------------------------
// prep kernel: wconv (10240 blocks) + bias concat (10) + embed (4096, 2 rows)
// ---------------------------------------------------------------------------
__global__ __launch_bounds__(256) void prep_kernel(WJobs jobs,
    const float* __restrict__ sbq, const float* __restrict__ sbk,
    const float* __restrict__ sbv, const float* __restrict__ cbk,
    const float* __restrict__ cbv, float* __restrict__ bqkv,
    float* __restrict__ bckv,
    const int* __restrict__ bytes_seq, const float* __restrict__ byte_emb,
    const float* __restrict__ ngram_emb, f16* __restrict__ out16)
{
  int bid = blockIdx.x;
  if (bid < 10240) {
    // ---- weight transpose+cast: fp32 [K][N] -> f16 [N][K] ----
    const int j = bid >> 10, tile = bid & 1023;
    if (tile >= jobs.tiles[j]) return;
    const int K = jobs.K[j], N = jobs.N[j];
    const int ntiles = N >> 5;
    const int kt = (tile / ntiles) << 5, nt = (tile % ntiles) << 5;
    __shared__ float T[32][33];
    const int t = threadIdx.x;
    const float* src = jobs.src[j];
    #pragma unroll
    for (int p = 0; p < 4; p++) {
      int lin = t + p * 256;
      int rr = lin >> 5, cc = lin & 31;
      T[rr][cc] = src[(size_t)(kt + rr) * N + nt + cc];
    }
    __syncthreads();
    f16* dst = jobs.dst[j];
    #pragma unroll
    for (int p = 0; p < 4; p++) {
      int lin = t + p * 256;
      int rr = lin >> 5, cc = lin & 31;
      dst[(size_t)(nt + rr) * K + kt + cc] = (f16)T[cc][rr];
    }
    return;
  }
  bid -= 10240;
  if (bid < 10) {
    // ---- bias concat ----
    int t = bid * 256 + threadIdx.x;
    if (t < 512)       bqkv[t] = sbq[t];
    else if (t < 1024) bqkv[t] = sbk[t - 512];
    else if (t < 1536) bqkv[t] = sbv[t - 1024];
    else if (t < 2048) bckv[t - 1536] = cbk[t - 1536];
    else if (t < 2560) bckv[t - 1536] = cbv[t - 2048];
    return;
  }
  bid -= 10;
  // ---- embedding + n-gram hash (2 rows per block) ----
  const int pos = bid * 2 + (threadIdx.x >> 7);
  const int b = pos / S_, s = pos % S_;
  const int* bs = bytes_seq + (size_t)b * S_;

  int w[8];
  #pragma unroll
  for (int k = 0; k < 8; k++) {
    int p = s - 7 + k;
    w[k] = (p >= 0) ? bs[p] : 0;
  }
  int idx[6];
  #pragma unroll
  for (int j = 0; j < 6; j++) {
    const int n = j + 3;
    int id = 0;
    if (s >= n - 1) {
      uint64_t h = 0;
      for (int k = 0; k < n; k++)
        h += (uint64_t)(uint32_t)w[8 - n + k] << (8 * k);
      long long sh = (long long)h;       // int64 wraparound semantics
      long long r = sh % (long long)V_;  // trunc-mod to floor-mod
      if (r < 0) r += V_;
      id = (int)r;
    }
    idx[j] = id;
  }
  const int d = (threadIdx.x & 127) * 4;
  float4 acc = *(const float4*)(byte_emb + (size_t)bs[s] * D_ + d);
  #pragma unroll
  for (int j = 0; j < 6; j++) {
    const float4 v = *(const float4*)(ngram_emb + ((size_t)j * V_ + idx[j]) * D_ + d);
    acc.x += v.x; acc.y += v.y; acc.z += v.z; acc.w += v.w;
  }
  const float inv7 = 1.0f / 7.0f;
  f16 t4[4];
  t4[0] = (f16)(acc.x * inv7); t4[1] = (f16)(acc.y * inv7);
  t4[2] = (f16)(acc.z * inv7); t4[3] = (f16)(acc.w * inv7);
  *(uint2*)(out16 + (size_t)pos * D_ + d) = *(uint2*)t4;
}

// ---------------------------------------------------------------------------
// f16 MFMA GEMM body (C^T accumulation), TRIPLE-buffered LDS, counted vmcnt.
// CONFLICT-FREE LDS: each row's four 16B K-chunks are stored ROTATED by
// (row>>1)&3 (rule #21: GLDS dest linear; the rotation is applied to the
// GLOBAL source address, and the frag read uses the matching rotated slot).
// 16-lane read phase then hits all 8 16B-slots mod 128B -> 2-way = free.
// 128xBN tile, BK=32, 4 waves, K compile-time.
// rowmap: A row r -> (r>>8)*S_ + rowmap[r] (patch gather fused).
// VTSTART>=0: cols >= VTSTART go to vt in [b][h][dh][s] layout (per-head V^T).
// bias may be nullptr (split-K partials; bias added in reduce).
// ---------------------------------------------------------------------------
template<typename OutT, int RELU, int BN, int VTSTART, int K>
__device__ __forceinline__ void gemm_body(
    const f16* __restrict__ A, const f16* __restrict__ Bt,
    const float* __restrict__ bias, OutT* __restrict__ C,
    int N, const int* __restrict__ rowmap,
    f16* __restrict__ vt, int bmi, int bni, int lda, int ldb)
{
  constexpr int NF = BN / 32;           // N-frags per wave
  constexpr int NT = K / 32;            // K-steps
  constexpr int GL = 2 + BN / 64;       // GLDS per thread per tile
  __shared__ __align__(16) f16 As[3][128 * 32];
  __shared__ __align__(16) f16 Bs[3][BN * 32];
  const int tid = threadIdx.x;
  const int l = tid & 63;
  const int lo4 = l & 15, hi2 = l >> 4;
  const int w = tid >> 6;
  const int wr = w >> 1, wc = w & 1;
  const int bm = bmi * 128, bn = bni * BN;

  // stage-side chunk rotation: slot s holds global chunk ((s&3)-(s>>3))&3
  // (per-row rotation by (row>>1)&3; row = s>>2, and (i*64)>>1 ≡ 0 mod 4)
  const int srot = ((tid & 3) - (tid >> 3)) & 3;

  const f16* ap[2];
  #pragma unroll
  for (int i = 0; i < 2; i++) {
    int r = bm + i * 64 + (tid >> 2);
    int ar = rowmap ? ((r >> 8) * S_ + rowmap[r]) : r;
    ap[i] = A + (size_t)ar * lda + srot * 8;
  }
  const f16* bp[BN / 64];
  #pragma unroll
  for (int i = 0; i < BN / 64; i++) {
    int c = i * 256 + tid;
    bp[i] = Bt + (size_t)(bn + (c >> 2)) * ldb + srot * 8;
  }

  f32x4 acc[4][NF];
  #pragma unroll
  for (int m = 0; m < 4; m++)
    #pragma unroll
    for (int n = 0; n < NF; n++) acc[m][n] = (f32x4){0.f, 0.f, 0.f, 0.f};

  // prologue: stage tiles 0 and 1
  #pragma unroll
  for (int i = 0; i < 2; i++)
    GLDS16(ap[i], &As[0][(i * 256 + tid) * 8]);
  #pragma unroll
  for (int i = 0; i < BN / 64; i++)
    GLDS16(bp[i], &Bs[0][(i * 256 + tid) * 8]);
  #pragma unroll
  for (int i = 0; i < 2; i++)
    GLDS16(ap[i] + 32, &As[1][(i * 256 + tid) * 8]);
  #pragma unroll
  for (int i = 0; i < BN / 64; i++)
    GLDS16(bp[i] + 32, &Bs[1][(i * 256 + tid) * 8]);

  // read-side rotated chunk slot: (hi2 + (lo4>>1)) & 3  (row&7 ≡ lo4&7 for
  // every m/n since all row offsets are multiples of 16)
  const int rslot = ((hi2 + (lo4 >> 1)) & 3) * 8;

  auto do_mma = [&](int c) {
    f16x8 af[4], bf[NF];
    const f16* pa = &As[c][(wr * 64 + lo4) * 32 + rslot];
    const f16* pb = &Bs[c][(wc * (BN / 2) + lo4) * 32 + rslot];
    #pragma unroll
    for (int m = 0; m < 4; m++) af[m] = *(const f16x8*)(pa + m * 16 * 32);
    #pragma unroll
    for (int n = 0; n < NF; n++) bf[n] = *(const f16x8*)(pb + n * 16 * 32);
    #pragma unroll
    for (int m = 0; m < 4; m++)
      #pragma unroll
      for (int n = 0; n < NF; n++)
        acc[m][n] = MFMA16(bf[n], af[m], acc[m][n]);   // C^T: swap operands
  };

  int cur = 0;
  #pragma unroll 3
  for (int t = 0; t < NT - 1; ++t) {
    wait_barrier<GL>();                  // tile t ready; tile t+1 in flight
    if (t + 2 < NT) {
      const int k0 = (t + 2) << 5;
      int stg = cur + 2; if (stg >= 3) stg -= 3;   // buffer freed by barrier
      #pragma unroll
      for (int i = 0; i < 2; i++)
        GLDS16(ap[i] + k0, &As[stg][(i * 256 + tid) * 8]);
      #pragma unroll
      for (int i = 0; i < BN / 64; i++)
        GLDS16(bp[i] + k0, &Bs[stg][(i * 256 + tid) * 8]);
    }
    do_mma(cur);
    cur = (cur == 2) ? 0 : cur + 1;
  }
  wait_barrier<0>();                     // final tile: full drain
  do_mma(cur);

  // SWAPPED C/D layout: product row = C-col = n*16 + hi2*4 + j,
  //                     product col = C-row = m*16 + lo4.
  if constexpr (VTSTART >= 0) {
    if (bn >= VTSTART) {
      // V^T epilogue: vt[((b*8+h)*64+d)*2048 + s]; scalar stores (d varies j)
      #pragma unroll
      for (int n = 0; n < NF; n++) {
        const int col0 = bn + wc * (BN / 2) + n * 16 + hi2 * 4;
        float bb[4] = {0.f, 0.f, 0.f, 0.f};
        if (bias) *(float4*)bb = *(const float4*)(bias + col0);
        #pragma unroll
        for (int m = 0; m < 4; m++) {
          const int s = bm + wr * 64 + m * 16 + lo4;
          #pragma unroll
          for (int j = 0; j < 4; j++) {
            const int dcol = col0 + j - VTSTART;
            vt[(((size_t)(s >> 11) * 8 + (dcol >> 6)) << 17) +
               ((size_t)(dcol & 63) << 11) + (s & 2047)] =
                (f16)(acc[m][n][j] + bb[j]);
          }
        }
      }
      return;
    }
  }

  #pragma unroll
  for (int n = 0; n < NF; n++) {
    const int col0 = bn + wc * (BN / 2) + n * 16 + hi2 * 4;
    float bb[4] = {0.f, 0.f, 0.f, 0.f};
    if (bias) *(float4*)bb = *(const float4*)(bias + col0);
    #pragma unroll
    for (int m = 0; m < 4; m++) {
      const int row = bm + wr * 64 + m * 16 + lo4;
      float v[4];
      #pragma unroll
      for (int j = 0; j < 4; j++) {
        v[j] = acc[m][n][j] + bb[j];
        if (RELU) v[j] = fmaxf(v[j], 0.f);
      }
      if constexpr (sizeof(OutT) == 2) {
        f16 t4[4];
        #pragma unroll
        for (int j = 0; j < 4; j++) t4[j] = (f16)v[j];
        *(uint2*)((f16*)C + (size_t)row * N + col0) = *(uint2*)t4;
      } else {
        float4 t4 = {v[0], v[1], v[2], v[3]};
        *(float4*)((float*)C + (size_t)row * N + col0) = t4;
      }
    }
  }
}

template<typename OutT, int RELU, int BN, int VTSTART, int K>
__global__ __launch_bounds__(256) void gemm_f16(
    const f16* __restrict__ A, const f16* __restrict__ Bt,
    const float* __restrict__ bias, OutT* __restrict__ C,
    int N, const int* __restrict__ rowmap, f16* __restrict__ vt)
{
  gemm_body<OutT, RELU, BN, VTSTART, K>(A, Bt, bias, C, N, rowmap, vt,
                                        blockIdx.x, blockIdx.y, K, K);
}

// ---------------------------------------------------------------------------
// merged cKV GEMM (512 blocks, V^T out) + gather-fused cQ GEMM (64 blocks)
// ---------------------------------------------------------------------------
__global__ __launch_bounds__(256) void ckv_cq_kernel(
    const f16* __restrict__ X, const f16* __restrict__ CKVT,
    const float* __restrict__ bckv, f16* __restrict__ CKV,
    f16* __restrict__ vt2, const f16* __restrict__ cWqT,
    const float* __restrict__ cbq, f16* __restrict__ CQ,
    const int* __restrict__ pidx)
{
  int bid = blockIdx.x;
  if (bid < 512) {
    gemm_body<f16, 0, 128, 512, 512>(X, CKVT, bckv, CKV, 1024,
                                     nullptr, vt2, bid >> 3, bid & 7, 512, 512);
  } else {
    bid -= 512;
    gemm_body<f16, 0, 64, -1, 512>(X, cWqT, cbq, CQ, 512,
                                   pidx, nullptr, bid >> 3, bid & 7, 512, 512);
  }
}

// ---------------------------------------------------------------------------
// final projection, split-K x4: partial[z] = CO[:, z*128:(z+1)*128] @ W-chunk
// ---------------------------------------------------------------------------
__global__ __launch_bounds__(256) void co_splitk(
    const f16* __restrict__ A, const f16* __restrict__ Bt,
    float* __restrict__ part)
{
  const int z = blockIdx.z;
  gemm_body<float, 0, 64, -1, 128>(A + z * 128, Bt + z * 128, nullptr,
      part + (size_t)z * NP_ * 512, 512, nullptr, nullptr,
      blockIdx.x, blockIdx.y, 512, 512);
}

__global__ __launch_bounds__(128) void co_reduce(
    const float* __restrict__ part, const float* __restrict__ bias,
    float* __restrict__ out)
{
  const int row = blockIdx.x;
  const int col = threadIdx.x * 4;
  float4 s = *(const float4*)(bias + col);
  #pragma unroll
  for (int c = 0; c < 4; c++) {
    const float4 v = *(const float4*)(part + ((size_t)c * NP_ + row) * 512 + col);
    s.x += v.x; s.y += v.y; s.z += v.z; s.w += v.w;
  }
  *(float4*)(out + (size_t)row * 512 + col) = s;
}

// ---------------------------------------------------------------------------
// f16 MFMA flash attention, max-free softmax (p = exp2(s)), swapped QK^T with
// permuted K-rows; P in registers via cvt_pkrtz + ds_bpermute. QG q-groups.
// CHUNKS>1: flash-decode split-KV, unnormalized f32 partials + lsum.
// V pre-transposed in global (VT[b][h][d][s]); staged to linear LDS via
// GLDS with XOR-swizzled global source; read with matching swizzle.
// ---------------------------------------------------------------------------
template<int QG, int CHUNKS>
__global__ __launch_bounds__(256) void attn_f16(
    const f16* __restrict__ Q, int qs,
    const f16* __restrict__ Kp, int kvs,
    const f16* __restrict__ VT, f16* __restrict__ O,
    float* __restrict__ Opart, float* __restrict__ Lpart, int NQ)
{
  constexpr int CL = S_ / CHUNKS;      // kv chunk length
  constexpr int NT = CL / 64;
  __shared__ __align__(16) f16 Ks[2][64][76];
  __shared__ __align__(16) f16 VtL[2][64 * 64];

  const int tid = threadIdx.x;
  const int w = tid >> 6, l = tid & 63;
  const int lo4 = l & 15, hi2 = l >> 4;
  const int lin = (CHUNKS == 1) ? blockIdx.x : (blockIdx.x & 127);
  const int c   = (CHUNKS == 1) ? 0 : (int)(blockIdx.x >> 7);
  const int h = lin & 7, b = (lin >> 3) & 3, qt = lin >> 5;

  const f16 qscale = (f16)0.18033688f;   // 0.125 * log2(e)
  f16x8 qf[QG][2];
  #pragma unroll
  for (int qg = 0; qg < QG; qg++) {
    const int qrow = qt * (64 * QG) + w * (16 * QG) + qg * 16 + lo4;
    const f16* Qp = Q + (size_t)(b * NQ + qrow) * qs + h * DH_ + hi2 * 8;
    qf[qg][0] = *(const f16x8*)(Qp);
    qf[qg][1] = *(const f16x8*)(Qp + 32);
    #pragma unroll
    for (int i = 0; i < 8; i++) { qf[qg][0][i] *= qscale; qf[qg][1][i] *= qscale; }
  }

  const int g2 = lo4 >> 2, j4 = lo4 & 3;
  const int kvp0 = 8 * g2 + j4;              // nf=0 (own block)
  const int kvp1 = 8 * (g2 ^ 2) + 4 + j4;    // nf=1 (partner block)
  const int pidx = (l ^ 32) << 2;            // bpermute partner index
  const int vswz = lo4 & 7;                  // V read swizzle

  const f16* Kb = Kp + ((size_t)b * S_ + c * CL) * kvs + h * DH_;
  const f16* VTbh = VT + (((size_t)(b * 8 + h)) << 17) + c * CL;

  float lsum[QG];
  f32x4 oacc[QG][4];
  #pragma unroll
  for (int qg = 0; qg < QG; qg++) {
    lsum[qg] = 0.f;
    #pragma unroll
    for (int df = 0; df < 4; df++) oacc[qg][df] = (f32x4){0.f, 0.f, 0.f, 0.f};
  }

  const int r0 = tid >> 3;   // K staging row 0..31
  const int c8 = tid & 7;    // staging 8-elem col chunk

  // prologue: stage tile 0
  #pragma unroll
  for (int i = 0; i < 2; i++) {
    int r = i * 32 + r0;
    GLDS16(VTbh + (size_t)r * 2048 + ((c8 ^ (r & 7)) * 8), &VtL[0][(i * 256 + tid) * 8]);
  }
  f16x8 kreg[2];
  #pragma unroll
  for (int i = 0; i < 2; i++)
    kreg[i] = *(const f16x8*)(Kb + (size_t)(i * 32 + r0) * kvs + c8 * 8);
  #pragma unroll
  for (int i = 0; i < 2; i++)
    *(f16x8*)(&Ks[0][i * 32 + r0][c8 * 8]) = kreg[i];
  __syncthreads();

  int cur = 0;
  for (int t = 0; t < NT; t++) {
    if (t + 1 < NT) {
      const int kt2 = (t + 1) * 64;
      #pragma unroll
      for (int i = 0; i < 2; i++) {
        int r = i * 32 + r0;
        GLDS16(VTbh + (size_t)r * 2048 + kt2 + ((c8 ^ (r & 7)) * 8),
               &VtL[cur ^ 1][(i * 256 + tid) * 8]);
      }
      #pragma unroll
      for (int i = 0; i < 2; i++)
        kreg[i] = *(const f16x8*)(Kb + (size_t)(kt2 + i * 32 + r0) * kvs + c8 * 8);
    }
    // S^T = K Q^T (log2 domain); K-fragments shared across q-groups
    f32x4 sacc[QG][4];
    #pragma unroll
    for (int nf = 0; nf < 4; nf++) {
      const int krow = ((nf & 1) ? kvp1 : kvp0) + (nf >> 1) * 32;
      f16x8 kf0 = *(const f16x8*)(&Ks[cur][krow][hi2 * 8]);
      f16x8 kf1 = *(const f16x8*)(&Ks[cur][krow][32 + hi2 * 8]);
      #pragma unroll
      for (int qg = 0; qg < QG; qg++) {
        f32x4 s = (f32x4){0.f, 0.f, 0.f, 0.f};
        s = MFMA16(kf0, qf[qg][0], s);
        s = MFMA16(kf1, qf[qg][1], s);
        sacc[qg][nf] = s;
      }
    }
    // p = exp2(s); per-lane partial row-sum; pack to f16 pairs
    uint32_t packs[QG][4][2];
    #pragma unroll
    for (int qg = 0; qg < QG; qg++)
      #pragma unroll
      for (int nf = 0; nf < 4; nf++) {
        float p0 = exp2f(sacc[qg][nf][0]);
        float p1 = exp2f(sacc[qg][nf][1]);
        float p2 = exp2f(sacc[qg][nf][2]);
        float p3 = exp2f(sacc[qg][nf][3]);
        lsum[qg] += (p0 + p1) + (p2 + p3);
        packs[qg][nf][0] = __builtin_bit_cast(uint32_t, __builtin_amdgcn_cvt_pkrtz(p0, p1));
        packs[qg][nf][1] = __builtin_bit_cast(uint32_t, __builtin_amdgcn_cvt_pkrtz(p2, p3));
      }
    // O^T += V^T P^T: V-fragments shared across q-groups
    #pragma unroll
    for (int ks = 0; ks < 2; ks++) {
      f16x8 pb[QG];
      #pragma unroll
      for (int qg = 0; qg < QG; qg++) {
        uint32_t w0 = packs[qg][2 * ks][0];
        uint32_t w1 = packs[qg][2 * ks][1];
        uint32_t w2 = (uint32_t)__builtin_amdgcn_ds_bpermute(pidx, (int)packs[qg][2 * ks + 1][0]);
        uint32_t w3 = (uint32_t)__builtin_amdgcn_ds_bpermute(pidx, (int)packs[qg][2 * ks + 1][1]);
        u32x4 bw = (u32x4){w0, w1, w2, w3};
        pb[qg] = __builtin_bit_cast(f16x8, bw);
      }
      #pragma unroll
      for (int df = 0; df < 4; df++) {
        const int r = df * 16 + lo4;
        const int cc = (ks * 4 + hi2) ^ vswz;
        f16x8 vf = *(const f16x8*)(&VtL[cur][r * 64 + cc * 8]);
        #pragma unroll
        for (int qg = 0; qg < QG; qg++)
          oacc[qg][df] = MFMA16(vf, pb[qg], oacc[qg][df]);
      }
    }
    if (t + 1 < NT) {
      #pragma unroll
      for (int i = 0; i < 2; i++)
        *(f16x8*)(&Ks[cur ^ 1][i * 32 + r0][c8 * 8]) = kreg[i];
    }
    __syncthreads();
    cur ^= 1;
  }

  #pragma unroll
  for (int qg = 0; qg < QG; qg++) {
    float r = lsum[qg];
    r += __shfl_xor(r, 16, 64);
    r += __shfl_xor(r, 32, 64);
    const int orow = qt * (64 * QG) + w * (16 * QG) + qg * 16 + lo4;
    if constexpr (CHUNKS == 1) {
      const float invl = 1.0f / r;
      f16* Ob = O + (size_t)(b * NQ + orow) * D_ + h * DH_ + hi2 * 4;
      #pragma unroll
      for (int df = 0; df < 4; df++) {
        f16 t4[4];
        #pragma unroll
        for (int j = 0; j < 4; j++) t4[j] = (f16)(oacc[qg][df][j] * invl);
        *(uint2*)(Ob + df * 16) = *(uint2*)t4;
      }
    } else {
      float* Op = Opart + ((size_t)c * NP_ + b * NQ + orow) * D_ + h * DH_ + hi2 * 4;
      #pragma unroll
      for (int df = 0; df < 4; df++) {
        float4 v = {oacc[qg][df][0], oacc[qg][df][1], oacc[qg][df][2], oacc[qg][df][3]};
        *(float4*)(Op + df * 16) = v;
      }
      if (hi2 == 0)
        Lpart[((size_t)c * NP_ + b * NQ + orow) * H_ + h] = r;
    }
  }
}

// ---------------------------------------------------------------------------
// combine split-KV partials: CO[row][col] = sum_c O_c / sum_c l_c
// ---------------------------------------------------------------------------
__global__ __launch_bounds__(128) void attn_reduce(
    const float* __restrict__ Opart, const float* __restrict__ Lpart,
    f16* __restrict__ CO)
{
  const int row = blockIdx.x;            // 0..NP_-1
  const int col = threadIdx.x * 4;
  const int h = col >> 6;
  float4 o = {0.f, 0.f, 0.f, 0.f};
  float ls = 0.f;
  #pragma unroll
  for (int c = 0; c < 4; c++) {
    const float4 v = *(const float4*)(Opart + ((size_t)c * NP_ + row) * D_ + col);
    o.x += v.x; o.y += v.y; o.z += v.z; o.w += v.w;
    ls += Lpart[((size_t)c * NP_ + row) * H_ + h];
  }
  const float inv = 1.0f / ls;
  f16 t4[4];
  t4[0] = (f16)(o.x * inv); t4[1] = (f16)(o.y * inv);
  t4[2] = (f16)(o.z * inv); t4[3] = (f16)(o.w * inv);
  *(uint2*)(CO + (size_t)row * D_ + col) = *(uint2*)t4;
}

// ---------------------------------------------------------------------------
// Fused residual + LayerNorm, all-f16 I/O (f32 math inside), 2 rows/block
// ---------------------------------------------------------------------------
__global__ __launch_bounds__(256) void ln_kernel(
    const f16* __restrict__ a, const f16* __restrict__ r,
    const float* __restrict__ g, const float* __restrict__ be,
    f16* __restrict__ out)
{
  const int row = blockIdx.x * 2 + (threadIdx.x >> 7);
  const int t = threadIdx.x & 127;
  const f16* ap = a + (size_t)row * D_ + t * 4;
  const f16* rp = r + (size_t)row * D_ + t * 4;
  uint2 au = *(const uint2*)ap, ru = *(const uint2*)rp;
  f16 a4[4], r4[4];
  *(uint2*)a4 = au; *(uint2*)r4 = ru;
  float x0 = (float)a4[0] + (float)r4[0];
  float x1 = (float)a4[1] + (float)r4[1];
  float x2 = (float)a4[2] + (float)r4[2];
  float x3 = (float)a4[3] + (float)r4[3];
  float sm = x0 + x1 + x2 + x3;
  float sq = x0*x0 + x1*x1 + x2*x2 + x3*x3;
  #pragma unroll
  for (int off = 32; off > 0; off >>= 1) {
    sm += __shfl_down(sm, off, 64);
    sq += __shfl_down(sq, off, 64);
  }
  __shared__ float s0[4], s1[4];
  if ((threadIdx.x & 63) == 0) { s0[threadIdx.x >> 6] = sm; s1[threadIdx.x >> 6] = sq; }
  __syncthreads();
  const int base = (threadIdx.x >> 7) * 2;
  const float Sm = s0[base] + s0[base + 1];
  const float Sq = s1[base] + s1[base + 1];
  const float mean = Sm * (1.0f / 512.0f);
  const float var  = Sq * (1.0f / 512.0f) - mean * mean;
  const float inv  = rsqrtf(var + 1e-5f);
  const float4 vg = *(const float4*)(g + t * 4);
  const float4 vb = *(const float4*)(be + t * 4);
  f16 o4[4];
  o4[0] = (f16)(vg.x * (x0 - mean) * inv + vb.x);
  o4[1] = (f16)(vg.y * (x1 - mean) * inv + vb.y);
  o4[2] = (f16)(vg.z * (x2 - mean) * inv + vb.z);
  o4[3] = (f16)(vg.w * (x3 - mean) * inv + vb.w);
  *(uint2*)(out + (size_t)row * D_ + t * 4) = *(uint2*)o4;
}

// ---------------------------------------------------------------------------
extern "C" void kernel_launch(void* const* d_in, const int* in_sizes, int n_in,
                              void* d_out, int out_size, void* d_ws, size_t ws_size,
                              hipStream_t stream) {
  const int*   bytes_seq = (const int*)  d_in[0];
  const int*   patch_idx = (const int*)  d_in[1];
  const float* byte_emb  = (const float*)d_in[2];
  const float* ngram_emb = (const float*)d_in[3];
  const float* sWq = (const float*)d_in[4];  const float* sbq = (const float*)d_in[5];
  const float* sWk = (const float*)d_in[6];  const float* sbk = (const float*)d_in[7];
  const float* sWv = (const float*)d_in[8];  const float* sbv = (const float*)d_in[9];
  const float* sWo = (const float*)d_in[10]; const float* sbo = (const float*)d_in[11];
  const float* ln1g = (const float*)d_in[12]; const float* ln1b = (const float*)d_in[13];
  const float* W1 = (const float*)d_in[14];  const float* b1 = (const float*)d_in[15];
  const float* W2 = (const float*)d_in[16];  const float* b2 = (const float*)d_in[17];
  const float* ln2g = (const float*)d_in[18]; const float* ln2b = (const float*)d_in[19];
  const float* cWq = (const float*)d_in[20]; const float* cbq = (const float*)d_in[21];
  const float* cWk = (const float*)d_in[22]; const float* cbk = (const float*)d_in[23];
  const float* cWv = (const float*)d_in[24]; const float* cbv = (const float*)d_in[25];
  const float* cWo = (const float*)d_in[26]; const float* cbo = (const float*)d_in[27];

  char* base = (char*)d_ws;
  const size_t MB = 1u << 20;
  f16* E16     = (f16*)(base + 0 * MB);       // 8 MB
  f16* TMP16   = (f16*)(base + 8 * MB);       // 8 MB
  f16* X116    = (f16*)(base + 16 * MB);      // 8 MB
  f16* X216    = (f16*)(base + 24 * MB);      // 8 MB
  f16* QKV16   = (f16*)(base + 32 * MB);      // [8192][1536] = 24 MB (V cols unused)
  f16* AT16    = (f16*)(base + 56 * MB);      // 8 MB
  f16* HID16   = (f16*)(base + 64 * MB);      // [8192][2048] = 32 MB
  f16* CKV16   = (f16*)(base + 96 * MB);      // [8192][1024] = 16 MB (V cols unused)
  f16* CQ16    = (f16*)(base + 112 * MB);     // 1 MB
  f16* CO16    = (f16*)(base + 113 * MB);     // 1 MB
  f16* WT      = (f16*)(base + 114 * MB);     // 8 MB transposed weights
  float* bqkv  = (float*)(base + 123 * MB);   // 1536 f32
  float* bckv  = bqkv + 1536;                 // 1024 f32
  f16* VT      = (f16*)(base + 124 * MB);     // [4][8][64][2048] = 8 MB (self V^T)
  f16* VT2     = (f16*)(base + 132 * MB);     // 8 MB (cross V^T)
  float* OPART = (float*)(base + 140 * MB);   // [4][1024][512] f32 = 8 MB
  float* LPART = (float*)(base + 148 * MB);   // [4][1024][8] f32 = 128 KB

  f16* QKVT = WT;                 // [1536][512]: Wq^T | Wk^T | Wv^T
  f16* sWoT = QKVT + 786432;
  f16* W1T  = sWoT + 262144;      // [2048][512]
  f16* W2T  = W1T + 1048576;      // [512][2048]
  f16* cWqT = W2T + 1048576;
  f16* CKVT = cWqT + 262144;      // [1024][512]: cWk^T | cWv^T
  f16* cWoT = CKVT + 524288;

  WJobs wj;
  {
    const float* wsrc[10] = {sWq, sWk, sWv, sWo, W1, W2, cWq, cWk, cWv, cWo};
    f16* wdst[10] = {QKVT, QKVT + 262144, QKVT + 524288, sWoT, W1T, W2T,
                     cWqT, CKVT, CKVT + 262144, cWoT};
    const int wK[10] = {512,512,512,512, 512,2048, 512,512,512,512};
    const int wN[10] = {512,512,512,512, 2048,512, 512,512,512,512};
    for (int i = 0; i < 10; i++) {
      wj.src[i] = wsrc[i]; wj.dst[i] = wdst[i];
      wj.K[i] = wK[i]; wj.N[i] = wN[i];
      wj.tiles[i] = (wK[i] >> 5) * (wN[i] >> 5);
    }
  }

  const dim3 blk256(256), blk128(128);

  prep_kernel<<<10240 + 10 + 4096, blk256, 0, stream>>>(
      wj, sbq, sbk, sbv, cbk, cbv, bqkv, bckv,
      bytes_seq, byte_emb, ngram_emb, E16);

  // fused QKV projection; V part straight to VT (per-head V^T)
  gemm_f16<f16, 0, 128, 1024, 512><<<dim3(64, 12), blk256, 0, stream>>>(
      E16, QKVT, bqkv, QKV16, 1536, nullptr, VT);

  // self-attention (128 q/block)
  attn_f16<2, 1><<<512, blk256, 0, stream>>>(
      QKV16, 1536, QKV16 + 512, 1536, VT, AT16, nullptr, nullptr, S_);

  // output projection + LN1
  gemm_f16<f16, 0, 64, -1, 512><<<dim3(64, 8), blk256, 0, stream>>>(
      AT16, sWoT, sbo, TMP16, 512, nullptr, nullptr);
  ln_kernel<<<N_/2, blk256, 0, stream>>>(E16, TMP16, ln1g, ln1b, X116);

  // FFN
  gemm_f16<f16, 1, 128, -1, 512><<<dim3(64, 16), blk256, 0, stream>>>(
      X116, W1T, b1, HID16, 2048, nullptr, nullptr);
  gemm_f16<f16, 0, 64, -1, 2048><<<dim3(64, 8), blk256, 0, stream>>>(
      HID16, W2T, b2, TMP16, 512, nullptr, nullptr);
  ln_kernel<<<N_/2, blk256, 0, stream>>>(X116, TMP16, ln2g, ln2b, X216);

  // cross: fused K|V projection (V^T to VT2) + gather-fused Q proj
  ckv_cq_kernel<<<576, blk256, 0, stream>>>(
      X216, CKVT, bckv, CKV16, VT2, cWqT, cbq, CQ16, patch_idx);
  // cross attention, split-KV x4 (flash-decode), then combine
  attn_f16<1, 4><<<512, blk256, 0, stream>>>(
      CQ16, 512, CKV16, 1024, VT2, nullptr, OPART, LPART, P_);
  attn_reduce<<<NP_, blk128, 0, stream>>>(OPART, LPART, CO16);

  // final projection: split-K x4 into OPART (reused), reduce+bias -> d_out
  co_splitk<<<dim3(8, 8, 4), blk256, 0, stream>>>(CO16, cWoT, OPART);
  co_reduce<<<NP_, blk128, 0, stream>>>(OPART, cbo, (float*)d_out);
}